// Round 5
// baseline (1635.895 us; speedup 1.0000x reference)
//
#include <hip/hip_runtime.h>
#include <math.h>

// Problem dims (fixed by reference setup_inputs)
#define BB 8
#define LL_ 2048
#define DD 1024
#define HH 2048

typedef unsigned short u16;
typedef __attribute__((ext_vector_type(8))) u16 u16x8;
typedef __attribute__((ext_vector_type(4))) u16 u16x4;
typedef __attribute__((ext_vector_type(8))) __bf16 bf16x8;
typedef __attribute__((ext_vector_type(4))) float f32x4;

__device__ __forceinline__ u16 f2bf(float f) {
    union { float f; unsigned u; } v; v.f = f;
    unsigned r = (v.u + 0x7FFFu + ((v.u >> 16) & 1u)) >> 16;
    return (u16)r;
}
__device__ __forceinline__ float bf2f(u16 h) {
    union { unsigned u; float f; } v; v.u = ((unsigned)h) << 16;
    return v.f;
}

// async global->LDS, 16 bytes per lane (global_load_lds_dwordx4)
__device__ __forceinline__ void gload16(const u16* g, u16* l) {
    __builtin_amdgcn_global_load_lds(
        (const __attribute__((address_space(1))) unsigned*)g,
        (__attribute__((address_space(3))) unsigned*)l, 16, 0, 0);
}

// ---------------------------------------------------------------------------
// bf16 MFMA GEMM, NT form: C[M,N] = A[M,K] @ Bt[N,K]^T.  A, Bt row-major bf16
// (u16 storage), fp32 accumulate, OutT output (float or u16/bf16).
// 128x128 tile, BK=32, 256 threads = 4 waves (2x2), each wave 64x64 via
// 4x4 frags of v_mfma_f32_16x16x32_bf16. global_load_lds(16B) staging into
// linear LDS (lane-order layout == staging order, required by the HW).
// CSKIP: skip blocks fully above the causal diagonal (scores).
// CKEND: limit K loop to i0+128 (P@V with strictly-causal P).
// Batched via blockIdx.z with element strides.
// ---------------------------------------------------------------------------
template <typename OutT, bool BIAS, bool RELU, bool CSKIP, bool CKEND>
__global__ __launch_bounds__(256) void gemm_bf16_kernel(
    const u16* __restrict__ A, const u16* __restrict__ Bt,
    const float* __restrict__ bias, OutT* __restrict__ C,
    int K, int N, float scale, long sAz, long sBz, long sCz)
{
    const int i0 = blockIdx.y * 128;   // M block
    const int n0 = blockIdx.x * 128;   // N block
    if (CSKIP && n0 > i0 + 127) return;

    A  += (long)blockIdx.z * sAz;
    Bt += (long)blockIdx.z * sBz;
    C  += (long)blockIdx.z * sCz;

    __shared__ u16 As[128 * 32];
    __shared__ u16 Bs[128 * 32];

    int kend = K;
    if (CKEND) { int ke = i0 + 128; kend = ke < K ? ke : K; }

    const int t   = threadIdx.x;
    const int wid = t >> 6, l = t & 63;
    const int wr  = wid >> 1, wc = wid & 1;   // wave 2x2 -> 64x64 each
    const int lg  = l >> 4, lr = l & 15;

    // staging: thread t covers (row = t>>2 [+64], k = (t&3)*8); LDS bytes t*16
    const int srow  = t >> 2;
    const int skoff = (t & 3) * 8;
    const u16* ga = A  + (long)(i0 + srow) * K + skoff;
    const u16* gb = Bt + (long)(n0 + srow) * K + skoff;
    u16* la = As + t * 8;
    u16* lb = Bs + t * 8;

    f32x4 acc[4][4];
    #pragma unroll
    for (int m = 0; m < 4; ++m)
        #pragma unroll
        for (int n = 0; n < 4; ++n)
            acc[m][n] = (f32x4){0.f, 0.f, 0.f, 0.f};

    for (int k0 = 0; k0 < kend; k0 += 32) {
        __syncthreads();   // previous iteration's LDS reads complete
        gload16(ga + k0, la);
        gload16(ga + (long)64 * K + k0, la + 64 * 32);
        gload16(gb + k0, lb);
        gload16(gb + (long)64 * K + k0, lb + 64 * 32);
        __syncthreads();   // staged tiles visible (vmcnt drained at barrier)

        bf16x8 af[4], bfr[4];
        #pragma unroll
        for (int m = 0; m < 4; ++m)
            af[m] = *(bf16x8*)(As + (wr * 64 + m * 16 + lr) * 32 + lg * 8);
        #pragma unroll
        for (int n = 0; n < 4; ++n)
            bfr[n] = *(bf16x8*)(Bs + (wc * 64 + n * 16 + lr) * 32 + lg * 8);
        #pragma unroll
        for (int m = 0; m < 4; ++m)
            #pragma unroll
            for (int n = 0; n < 4; ++n)
                acc[m][n] = __builtin_amdgcn_mfma_f32_16x16x32_bf16(
                    af[m], bfr[n], acc[m][n], 0, 0, 0);
    }

    // epilogue: C frag mapping col = lane&15, row = (lane>>4)*4 + r
    #pragma unroll
    for (int n = 0; n < 4; ++n) {
        const int col = n0 + wc * 64 + n * 16 + lr;
        const float bv = BIAS ? bias[col] : 0.f;
        #pragma unroll
        for (int m = 0; m < 4; ++m) {
            const int row0 = i0 + wr * 64 + m * 16 + lg * 4;
            #pragma unroll
            for (int r = 0; r < 4; ++r) {
                float val = acc[m][n][r] * scale + bv;
                if (RELU) val = fmaxf(val, 0.f);
                if (sizeof(OutT) == 4) {
                    ((float*)C)[(long)(row0 + r) * N + col] = val;
                } else {
                    ((u16*)C)[(long)(row0 + r) * N + col] = f2bf(val);
                }
            }
        }
    }
}

// ---------------------------------------------------------------------------
// fp32 -> bf16 elementwise convert (n multiple of 2048)
// ---------------------------------------------------------------------------
__global__ __launch_bounds__(256) void f2b_kernel(
    const float* __restrict__ in, u16* __restrict__ out)
{
    const long i = ((long)blockIdx.x * 256 + threadIdx.x) * 8;
    const float4 a = *(const float4*)(in + i);
    const float4 b = *(const float4*)(in + i + 4);
    u16x8 o;
    o[0] = f2bf(a.x); o[1] = f2bf(a.y); o[2] = f2bf(a.z); o[3] = f2bf(a.w);
    o[4] = f2bf(b.x); o[5] = f2bf(b.y); o[6] = f2bf(b.z); o[7] = f2bf(b.w);
    *(u16x8*)(out + i) = o;
}

// ---------------------------------------------------------------------------
// transpose fp32 [R][C] -> bf16 [C][R]  (weights; R,C multiples of 32)
// ---------------------------------------------------------------------------
__global__ __launch_bounds__(256) void transpose_f2b_kernel(
    const float* __restrict__ in, u16* __restrict__ out, int R, int C)
{
    __shared__ float tile[32][33];
    const int tx = threadIdx.x & 31, ty = threadIdx.x >> 5;
    const int c0 = blockIdx.x * 32, r0 = blockIdx.y * 32;
    #pragma unroll
    for (int i = 0; i < 4; ++i)
        tile[ty + i * 8][tx] = in[(long)(r0 + ty + i * 8) * C + c0 + tx];
    __syncthreads();
    #pragma unroll
    for (int i = 0; i < 4; ++i)
        out[(long)(c0 + ty + i * 8) * R + r0 + tx] = f2bf(tile[tx][ty + i * 8]);
}

// ---------------------------------------------------------------------------
// transpose bf16 [R][C] -> bf16 [C][R], z-batched (V transpose)
// ---------------------------------------------------------------------------
__global__ __launch_bounds__(256) void transpose_b2b_kernel(
    const u16* __restrict__ in, u16* __restrict__ out, int R, int C,
    long sIz, long sOz)
{
    __shared__ u16 tile[32][33];
    in  += (long)blockIdx.z * sIz;
    out += (long)blockIdx.z * sOz;
    const int tx = threadIdx.x & 31, ty = threadIdx.x >> 5;
    const int c0 = blockIdx.x * 32, r0 = blockIdx.y * 32;
    #pragma unroll
    for (int i = 0; i < 4; ++i)
        tile[ty + i * 8][tx] = in[(long)(r0 + ty + i * 8) * C + c0 + tx];
    __syncthreads();
    #pragma unroll
    for (int i = 0; i < 4; ++i)
        out[(long)(c0 + ty + i * 8) * R + r0 + tx] = tile[tx][ty + i * 8];
}

// ---------------------------------------------------------------------------
// Row softmax on bf16 scores in place (-> probabilities bf16). fp32 math.
// Causal mask applied by index (garbage in skipped blocks never used).
// ---------------------------------------------------------------------------
__global__ __launch_bounds__(256) void softmax_bf16_kernel(
    u16* __restrict__ S, int L, int causal, long sSz)
{
    const int i = blockIdx.x;
    u16* row = S + (long)blockIdx.y * sSz + (long)i * L;
    const int t = threadIdx.x;

    const u16x8 rv = *(const u16x8*)(row + t * 8);
    float v[8];
    float m = -INFINITY;
    #pragma unroll
    for (int e = 0; e < 8; ++e) {
        const int j = t * 8 + e;
        float val = (causal && j > i) ? -INFINITY : bf2f(rv[e]);
        v[e] = val;
        m = fmaxf(m, val);
    }
    #pragma unroll
    for (int o = 32; o > 0; o >>= 1) m = fmaxf(m, __shfl_down(m, o, 64));
    __shared__ float redm[4];
    if ((t & 63) == 0) redm[t >> 6] = m;
    __syncthreads();
    m = fmaxf(fmaxf(redm[0], redm[1]), fmaxf(redm[2], redm[3]));

    float sum = 0.f;
    #pragma unroll
    for (int e = 0; e < 8; ++e) { float ex = expf(v[e] - m); v[e] = ex; sum += ex; }
    #pragma unroll
    for (int o = 32; o > 0; o >>= 1) sum += __shfl_down(sum, o, 64);
    __shared__ float reds[4];
    if ((t & 63) == 0) reds[t >> 6] = sum;
    __syncthreads();
    sum = reds[0] + reds[1] + reds[2] + reds[3];

    const float inv = 1.0f / sum;
    u16x8 ov;
    #pragma unroll
    for (int e = 0; e < 8; ++e) ov[e] = f2bf(v[e] * inv);
    *(u16x8*)(row + t * 8) = ov;
}

// ---------------------------------------------------------------------------
// out = LayerNorm(x + y; gamma, beta, eps=1e-3), D=1024; optional bf16 copy.
// ---------------------------------------------------------------------------
__global__ __launch_bounds__(256) void add_ln_kernel(
    const float* __restrict__ X, const float* __restrict__ Y,
    const float* __restrict__ gamma, const float* __restrict__ beta,
    float* __restrict__ out, u16* __restrict__ outb, int D)
{
    const long r = blockIdx.x;
    const int t = threadIdx.x;
    const float4 x = *(const float4*)&X[r * D + t * 4];
    const float4 y = *(const float4*)&Y[r * D + t * 4];
    float s0 = x.x + y.x, s1 = x.y + y.y, s2 = x.z + y.z, s3 = x.w + y.w;

    float sum = s0 + s1 + s2 + s3;
    float sq  = s0 * s0 + s1 * s1 + s2 * s2 + s3 * s3;
    #pragma unroll
    for (int o = 32; o > 0; o >>= 1) {
        sum += __shfl_down(sum, o, 64);
        sq  += __shfl_down(sq, o, 64);
    }
    __shared__ float rsum[4], rsq[4];
    if ((t & 63) == 0) { rsum[t >> 6] = sum; rsq[t >> 6] = sq; }
    __syncthreads();
    sum = rsum[0] + rsum[1] + rsum[2] + rsum[3];
    sq  = rsq[0] + rsq[1] + rsq[2] + rsq[3];

    const float mu   = sum / (float)D;
    const float var  = sq / (float)D - mu * mu;
    const float rstd = rsqrtf(var + 1e-3f);

    const float4 g = *(const float4*)&gamma[t * 4];
    const float4 b = *(const float4*)&beta[t * 4];
    float4 o;
    o.x = (s0 - mu) * rstd * g.x + b.x;
    o.y = (s1 - mu) * rstd * g.y + b.y;
    o.z = (s2 - mu) * rstd * g.z + b.z;
    o.w = (s3 - mu) * rstd * g.w + b.w;
    *(float4*)&out[r * D + t * 4] = o;
    if (outb) {
        u16x4 ob;
        ob[0] = f2bf(o.x); ob[1] = f2bf(o.y); ob[2] = f2bf(o.z); ob[3] = f2bf(o.w);
        *(u16x4*)&outb[r * D + t * 4] = ob;
    }
}

// ---------------------------------------------------------------------------
extern "C" void kernel_launch(void* const* d_in, const int* in_sizes, int n_in,
                              void* d_out, int out_size, void* d_ws, size_t ws_size,
                              hipStream_t stream)
{
    const int B = BB, L = LL_, D = DD, H = HH;
    const long LD  = (long)L * D;        // 2M elems
    const long LLs = (long)L * L;        // 4M elems
    const long BLD = (long)B * LD;       // 16.78M elems
    const int  BL  = B * L;              // 16384

    const float* x     = (const float*)d_in[0];
    const float* ctx   = (const float*)d_in[1];
    const float* Wk_s  = (const float*)d_in[2];
    const float* Wv_s  = (const float*)d_in[3];
    const float* Wq_s  = (const float*)d_in[4];
    const float* Wk_c  = (const float*)d_in[5];
    const float* Wv_c  = (const float*)d_in[6];
    const float* Wq_c  = (const float*)d_in[7];
    const float* W1    = (const float*)d_in[8];
    const float* b1    = (const float*)d_in[9];
    const float* W2    = (const float*)d_in[10];
    const float* b2    = (const float*)d_in[11];
    const float* gamma = (const float*)d_in[12];
    const float* beta  = (const float*)d_in[13];
    float* out = (float*)d_out;

    // ---- workspace layout (bump allocator) ----
    size_t ofs = 0;
    auto alloc = [&](size_t bytes) -> char* {
        char* p = (char*)d_ws + ofs;
        ofs += (bytes + 255) & ~(size_t)255;
        return p;
    };
    u16* WkTs = (u16*)alloc((size_t)D * D * 2);
    u16* WvTs = (u16*)alloc((size_t)D * D * 2);
    u16* WqTs = (u16*)alloc((size_t)D * D * 2);
    u16* WkTc = (u16*)alloc((size_t)D * D * 2);
    u16* WvTc = (u16*)alloc((size_t)D * D * 2);
    u16* WqTc = (u16*)alloc((size_t)D * D * 2);
    u16* W1T  = (u16*)alloc((size_t)D * H * 2);   // [H][D]
    u16* W2T  = (u16*)alloc((size_t)H * D * 2);   // [D][H]
    u16* actb1 = (u16*)alloc((size_t)BLD * 2);    // xb -> ctxb -> o2b
    u16* actb2 = (u16*)alloc((size_t)BLD * 2);    // o1b
    float* o2  = (float*)alloc((size_t)BLD * 4);
    char* scratch = (char*)d_ws + ofs;
    const size_t remain = ws_size > ofs ? ws_size - ofs : 0;

    // attention batch-group scratch: q,k,v,vt (bf16 LD each) + P (bf16 LLs)
    // + attn (fp32 LD) per batch
    const size_t per_b = (size_t)(4 * LD + LLs) * 2 + (size_t)LD * 4;
    long gl = (long)(remain / per_b);
    const int g = gl < 1 ? 1 : (gl > B ? B : (int)gl);

    u16* qb  = (u16*)scratch;
    u16* kb  = qb + (size_t)g * LD;
    u16* vb  = kb + (size_t)g * LD;
    u16* vtb = vb + (size_t)g * LD;
    u16* Pb  = vtb + (size_t)g * LD;
    float* attnb = (float*)(Pb + (size_t)g * LLs);

    const float scale = 1.0f / sqrtf((float)L);
    const dim3 blk(256);

    // ---- weight transposes (fp32 -> bf16, [K][N] -> [N][K]) ----
    transpose_f2b_kernel<<<dim3(D/32, D/32), blk, 0, stream>>>(Wk_s, WkTs, D, D);
    transpose_f2b_kernel<<<dim3(D/32, D/32), blk, 0, stream>>>(Wv_s, WvTs, D, D);
    transpose_f2b_kernel<<<dim3(D/32, D/32), blk, 0, stream>>>(Wq_s, WqTs, D, D);
    transpose_f2b_kernel<<<dim3(D/32, D/32), blk, 0, stream>>>(Wk_c, WkTc, D, D);
    transpose_f2b_kernel<<<dim3(D/32, D/32), blk, 0, stream>>>(Wv_c, WvTc, D, D);
    transpose_f2b_kernel<<<dim3(D/32, D/32), blk, 0, stream>>>(Wq_c, WqTc, D, D);
    transpose_f2b_kernel<<<dim3(H/32, D/32), blk, 0, stream>>>(W1, W1T, D, H);
    transpose_f2b_kernel<<<dim3(D/32, H/32), blk, 0, stream>>>(W2, W2T, H, D);

    // attention phase: per batch-group proj + scores + softmax + PV + add/LN
    auto attn_phase = [&](const u16* qsrcb, const u16* kvsrcb,
                          const u16* WqT, const u16* WkT, const u16* WvT,
                          const float* resid, float* dst, u16* dstb, int causal) {
        for (int b0 = 0; b0 < B; b0 += g) {
            const int gb = (B - b0) < g ? (B - b0) : g;
            const long off = (long)b0 * LD;
            gemm_bf16_kernel<u16, false, false, false, false>
                <<<dim3(D/128, gb*L/128), blk, 0, stream>>>(
                    qsrcb + off, WqT, nullptr, qb, D, D, 1.f, 0, 0, 0);
            gemm_bf16_kernel<u16, false, false, false, false>
                <<<dim3(D/128, gb*L/128), blk, 0, stream>>>(
                    kvsrcb + off, WkT, nullptr, kb, D, D, 1.f, 0, 0, 0);
            gemm_bf16_kernel<u16, false, false, false, false>
                <<<dim3(D/128, gb*L/128), blk, 0, stream>>>(
                    kvsrcb + off, WvT, nullptr, vb, D, D, 1.f, 0, 0, 0);
            transpose_b2b_kernel<<<dim3(D/32, L/32, gb), blk, 0, stream>>>(
                vb, vtb, L, D, LD, LD);
            if (causal) {
                gemm_bf16_kernel<u16, false, false, true, false>
                    <<<dim3(L/128, L/128, gb), blk, 0, stream>>>(
                        qb, kb, nullptr, Pb, D, L, scale, LD, LD, LLs);
            } else {
                gemm_bf16_kernel<u16, false, false, false, false>
                    <<<dim3(L/128, L/128, gb), blk, 0, stream>>>(
                        qb, kb, nullptr, Pb, D, L, scale, LD, LD, LLs);
            }
            softmax_bf16_kernel<<<dim3(L, gb), blk, 0, stream>>>(Pb, L, causal, LLs);
            if (causal) {
                gemm_bf16_kernel<float, false, false, false, true>
                    <<<dim3(D/128, L/128, gb), blk, 0, stream>>>(
                        Pb, vtb, nullptr, attnb, L, D, 1.f, LLs, LD, LD);
            } else {
                gemm_bf16_kernel<float, false, false, false, false>
                    <<<dim3(D/128, L/128, gb), blk, 0, stream>>>(
                        Pb, vtb, nullptr, attnb, L, D, 1.f, LLs, LD, LD);
            }
            add_ln_kernel<<<dim3(gb * L), blk, 0, stream>>>(
                resid + off, attnb, gamma, beta, dst + off,
                dstb ? dstb + off : nullptr, D);
        }
    };

    // ---- Phase A: self-attention (causal). o1 fp32 -> d_out, o1b -> actb2 ----
    f2b_kernel<<<dim3(BLD / 2048), blk, 0, stream>>>(x, actb1);       // xb
    attn_phase(actb1, actb1, WqTs, WkTs, WvTs, x, out, actb2, 1);

    // ---- Phase B: cross-attention. o2 fp32 -> ws, o2b -> actb1 ----
    f2b_kernel<<<dim3(BLD / 2048), blk, 0, stream>>>(ctx, actb1);     // ctxb
    // o2b overwrites actb1 rows only after that group's k/v are consumed.
    attn_phase(actb2, actb1, WqTc, WkTc, WvTc, out, o2, actb1, 0);

    // ---- Phase C: FFN + LN, row-chunked through scratch ----
    {
        long mc = (long)(remain / ((size_t)H * 2 + (size_t)D * 4));
        mc = (mc / 128) * 128;
        if (mc > BL) mc = BL;
        if (mc < 128) mc = 128;
        for (long m0 = 0; m0 < BL; m0 += mc) {
            const long rows = (BL - m0) < mc ? (BL - m0) : mc;
            u16* h = (u16*)scratch;                          // [rows, H] bf16
            float* ff = (float*)(scratch + (size_t)rows * H * 2);  // [rows, D]
            gemm_bf16_kernel<u16, true, true, false, false>
                <<<dim3(H/128, rows/128), blk, 0, stream>>>(
                    actb1 + m0 * D, W1T, b1, h, D, H, 1.f, 0, 0, 0);
            gemm_bf16_kernel<float, true, false, false, false>
                <<<dim3(D/128, rows/128), blk, 0, stream>>>(
                    h, W2T, b2, ff, H, D, 1.f, 0, 0, 0);
            add_ln_kernel<<<dim3(rows), blk, 0, stream>>>(
                o2 + m0 * D, ff, gamma, beta, out + m0 * D, nullptr, D);
        }
    }
}

// Round 7
// 1509.071 us; speedup vs baseline: 1.0840x; 1.0840x over previous
//
#include <hip/hip_runtime.h>
#include <math.h>

// Problem dims (fixed by reference setup_inputs)
#define BB 8
#define LL_ 2048
#define DD 1024
#define HH 2048

typedef unsigned short u16;
typedef __attribute__((ext_vector_type(8))) u16 u16x8;
typedef __attribute__((ext_vector_type(4))) u16 u16x4;
typedef __attribute__((ext_vector_type(8))) __bf16 bf16x8;
typedef __attribute__((ext_vector_type(4))) float f32x4;

__device__ __forceinline__ u16 f2bf(float f) {
    union { float f; unsigned u; } v; v.f = f;
    unsigned r = (v.u + 0x7FFFu + ((v.u >> 16) & 1u)) >> 16;
    return (u16)r;
}
__device__ __forceinline__ float bf2f(u16 h) {
    union { unsigned u; float f; } v; v.u = ((unsigned)h) << 16;
    return v.f;
}

// async global->LDS, 16 bytes per lane (global_load_lds_dwordx4)
__device__ __forceinline__ void gload16(const u16* g, u16* l) {
    __builtin_amdgcn_global_load_lds(
        (const __attribute__((address_space(1))) unsigned*)g,
        (__attribute__((address_space(3))) unsigned*)l, 16, 0, 0);
}

// MFMA quadrant: 4m x 2n frags x 2 ksub = 16 MFMA, constexpr acc indices.
template <int MH, int NH>
__device__ __forceinline__ void quad(f32x4 (&acc)[8][4],
                                     const bf16x8 (&aF)[4][2],
                                     const bf16x8 (&bF)[2][2]) {
    #pragma unroll
    for (int mq = 0; mq < 4; ++mq)
        #pragma unroll
        for (int nq = 0; nq < 2; ++nq)
            #pragma unroll
            for (int ks = 0; ks < 2; ++ks)
                acc[MH * 4 + mq][NH * 2 + nq] =
                    __builtin_amdgcn_mfma_f32_16x16x32_bf16(
                        aF[mq][ks], bF[nq][ks], acc[MH * 4 + mq][NH * 2 + nq],
                        0, 0, 0);
}

// ---------------------------------------------------------------------------
// 256x256 8-phase bf16 MFMA GEMM, NT form: C[M,N] = A[M,K] @ Bt[N,K]^T.
// 512 threads = 8 waves (2x4); wave tile 128x64 = 8x4 frags of 16x16x32.
// BK=64 K-tiles, double-buffered 128 KiB LDS, half-tile (128 rows x 64 k)
// staging via global_load_lds with inverse-swizzled source; ds_read uses
// byte ^= ((row&7)<<4) swizzle -> conflict-free b128 reads.
// Counted vmcnt(4) at phases 4/8 only.  STG never skips: past-the-end tiles
// re-read tile nt-1 (source clamped) into the dead destination slot, so the
// vmcnt ledger is uniform (12 outstanding at each P4/P8; retire 8 = through
// A of the next-needed tile).  Race audit: each region's restage issues
// >= 1 barrier after that region's last ds_read; concurrent stage/read
// regions are disjoint in every phase.
// CSKIP: skip blocks fully above causal diagonal.  CKEND: kend=i0+256 (P@V).
// ---------------------------------------------------------------------------
template <typename OutT, bool BIAS, bool RELU, bool CSKIP, bool CKEND>
__global__ __launch_bounds__(512, 2) void gemm256_kernel(
    const u16* __restrict__ A, const u16* __restrict__ Bt,
    const float* __restrict__ bias, OutT* __restrict__ C,
    int K, int N, float scale, long sAz, long sBz, long sCz)
{
    const int i0 = blockIdx.y * 256;   // M block
    const int n0 = blockIdx.x * 256;   // N block
    if (CSKIP && n0 > i0 + 255) return;

    A  += (long)blockIdx.z * sAz;
    Bt += (long)blockIdx.z * sBz;
    C  += (long)blockIdx.z * sCz;

    // 2 bufs x (A: 2 halves + B: 2 halves) x 16 KiB = 128 KiB
    __shared__ u16 lds[65536];

    int kend = K;
    if (CKEND) { int ke = i0 + 256; kend = ke < K ? ke : K; }
    const int nt = kend >> 6;          // K-tiles of 64 (>=4, even)

    const int t   = threadIdx.x;
    const int wid = t >> 6, l = t & 63;
    const int wr  = wid >> 2, wc = wid & 3;   // 2x4 wave grid
    const int lg  = l >> 4,  lr = l & 15;

    // staging: thread t -> half-tile row srow(+64), logical k-chunk sch
    // (inverse swizzle so linear LDS dest yields swizzled layout)
    const int srow = t >> 3;                    // 0..63
    const int sch  = (t & 7) ^ (srow & 7);      // logical 8-elem chunk

    // swizzled read slots (u16 units): chunk c at byte (c ^ (row&7))*16
    const int slot0 = ((lg) ^ (lr & 7)) * 8;        // ksub=0, chunk=lg
    const int slot1 = ((4 + lg) ^ (lr & 7)) * 8;    // ksub=1, chunk=4+lg

    f32x4 acc[8][4];
    #pragma unroll
    for (int m = 0; m < 8; ++m)
        #pragma unroll
        for (int n = 0; n < 4; ++n)
            acc[m][n] = (f32x4){0.f, 0.f, 0.f, 0.f};

    bf16x8 aF[4][2], bF0[2][2], bF1[2][2];

    auto readA_f = [&](int bufb, int mh) {
        const u16* base = lds + bufb + wr * 8192 + mh * 4096 + lr * 64;
        #pragma unroll
        for (int mq = 0; mq < 4; ++mq) {
            aF[mq][0] = *(const bf16x8*)(base + mq * 1024 + slot0);
            aF[mq][1] = *(const bf16x8*)(base + mq * 1024 + slot1);
        }
    };
    auto readB_f = [&](int bufb, int nh, bf16x8 (&bf)[2][2]) {
        const u16* base = lds + bufb + 16384 + (wc >> 1) * 8192 +
                          (wc & 1) * 4096 + nh * 2048 + lr * 64;
        #pragma unroll
        for (int nq = 0; nq < 2; ++nq) {
            bf[nq][0] = *(const bf16x8*)(base + nq * 1024 + slot0);
            bf[nq][1] = *(const bf16x8*)(base + nq * 1024 + slot1);
        }
    };
    // which: 0=A-half0, 1=A-half1, 2=B-half0, 3=B-half1.
    // Source tile clamped to nt-1 (dest slot from the ORIGINAL tile parity is
    // dead when tile >= nt) so the vmcnt ledger stays uniform.
    auto STG = [&](int tile, int which) {
        const int  st  = tile < nt ? tile : nt - 1;
        const bool isB = which >= 2;
        const int  h   = which & 1;
        const u16* src = isB ? Bt : A;
        const int  r0  = (isB ? n0 : i0) + h * 128 + srow;
        const long g   = (long)r0 * K + st * 64 + sch * 8;
        u16* d = lds + (tile & 1) * 32768 + (isB ? 16384 : 0) + h * 8192 + t * 8;
        gload16(src + g, d);
        gload16(src + g + (long)64 * K, d + 4096);
    };

#define PHASE(MH, NH, RA, RB, BF, BUFB, STILE, SWHICH, VM4)                 \
    {                                                                       \
        if (RA) readA_f(BUFB, MH);                                          \
        if (RB) readB_f(BUFB, NH, BF);                                      \
        STG(STILE, SWHICH);                                                 \
        if (VM4) asm volatile("s_waitcnt vmcnt(4)" ::: "memory");           \
        asm volatile("s_barrier" ::: "memory");                             \
        __builtin_amdgcn_s_setprio(1);                                      \
        quad<MH, NH>(acc, aF, BF);                                          \
        __builtin_amdgcn_s_setprio(0);                                      \
        asm volatile("s_barrier" ::: "memory");                             \
    }

    // prologue: T0 {B0,B1,A0,A1}, T1 {B0,B1}; wait all but newest 2 halves
    STG(0, 2); STG(0, 3); STG(0, 0); STG(0, 1);
    STG(1, 2); STG(1, 3);
    asm volatile("s_waitcnt vmcnt(4)" ::: "memory");
    asm volatile("s_barrier" ::: "memory");

    for (int j = 0; j < nt; j += 2) {
        // K-tile j in buf0 (phases 1-4), j+1 in buf1 (phases 5-8)
        PHASE(0, 0, 1, 1, bF0, 0,     j + 1, 0, 0)   // stage A0(j+1)
        PHASE(0, 1, 0, 1, bF1, 0,     j + 1, 1, 0)   // stage A1(j+1)
        PHASE(1, 1, 1, 0, bF1, 0,     j + 2, 2, 0)   // stage B0(j+2)
        PHASE(1, 0, 0, 0, bF0, 0,     j + 2, 3, 1)   // stage B1(j+2), vmcnt(4)
        PHASE(0, 0, 1, 1, bF0, 32768, j + 2, 0, 0)   // stage A0(j+2)
        PHASE(0, 1, 0, 1, bF1, 32768, j + 2, 1, 0)   // stage A1(j+2)
        PHASE(1, 1, 1, 0, bF1, 32768, j + 3, 2, 0)   // stage B0(j+3)
        PHASE(1, 0, 0, 0, bF0, 32768, j + 3, 3, 1)   // stage B1(j+3), vmcnt(4)
    }
#undef PHASE

    // drain in-flight LDS-DMA (dead-slot stages) before epilogue / endpgm
    asm volatile("s_waitcnt vmcnt(0)" ::: "memory");

    // epilogue: C frag mapping col = lane&15, row = (lane>>4)*4 + r
    #pragma unroll
    for (int nj = 0; nj < 4; ++nj) {
        const int col = n0 + wc * 64 + nj * 16 + lr;
        const float bv = BIAS ? bias[col] : 0.f;
        #pragma unroll
        for (int mi = 0; mi < 8; ++mi) {
            const int row0 = i0 + wr * 128 + mi * 16 + lg * 4;
            #pragma unroll
            for (int r = 0; r < 4; ++r) {
                float val = acc[mi][nj][r] * scale + bv;
                if (RELU) val = fmaxf(val, 0.f);
                if (sizeof(OutT) == 4) {
                    ((float*)C)[(long)(row0 + r) * N + col] = val;
                } else {
                    ((u16*)C)[(long)(row0 + r) * N + col] = f2bf(val);
                }
            }
        }
    }
}

// ---------------------------------------------------------------------------
// fp32 -> bf16 elementwise convert (n multiple of 2048)
// ---------------------------------------------------------------------------
__global__ __launch_bounds__(256) void f2b_kernel(
    const float* __restrict__ in, u16* __restrict__ out)
{
    const long i = ((long)blockIdx.x * 256 + threadIdx.x) * 8;
    const float4 a = *(const float4*)(in + i);
    const float4 b = *(const float4*)(in + i + 4);
    u16x8 o;
    o[0] = f2bf(a.x); o[1] = f2bf(a.y); o[2] = f2bf(a.z); o[3] = f2bf(a.w);
    o[4] = f2bf(b.x); o[5] = f2bf(b.y); o[6] = f2bf(b.z); o[7] = f2bf(b.w);
    *(u16x8*)(out + i) = o;
}

// ---------------------------------------------------------------------------
// transpose fp32 [R][C] -> bf16 [C][R]  (weights; R,C multiples of 32)
// ---------------------------------------------------------------------------
__global__ __launch_bounds__(256) void transpose_f2b_kernel(
    const float* __restrict__ in, u16* __restrict__ out, int R, int C)
{
    __shared__ float tile[32][33];
    const int tx = threadIdx.x & 31, ty = threadIdx.x >> 5;
    const int c0 = blockIdx.x * 32, r0 = blockIdx.y * 32;
    #pragma unroll
    for (int i = 0; i < 4; ++i)
        tile[ty + i * 8][tx] = in[(long)(r0 + ty + i * 8) * C + c0 + tx];
    __syncthreads();
    #pragma unroll
    for (int i = 0; i < 4; ++i)
        out[(long)(c0 + ty + i * 8) * R + r0 + tx] = f2bf(tile[tx][ty + i * 8]);
}

// ---------------------------------------------------------------------------
// transpose bf16 [R][C] -> bf16 [C][R], z-batched (V transpose)
// ---------------------------------------------------------------------------
__global__ __launch_bounds__(256) void transpose_b2b_kernel(
    const u16* __restrict__ in, u16* __restrict__ out, int R, int C,
    long sIz, long sOz)
{
    __shared__ u16 tile[32][33];
    in  += (long)blockIdx.z * sIz;
    out += (long)blockIdx.z * sOz;
    const int tx = threadIdx.x & 31, ty = threadIdx.x >> 5;
    const int c0 = blockIdx.x * 32, r0 = blockIdx.y * 32;
    #pragma unroll
    for (int i = 0; i < 4; ++i)
        tile[ty + i * 8][tx] = in[(long)(r0 + ty + i * 8) * C + c0 + tx];
    __syncthreads();
    #pragma unroll
    for (int i = 0; i < 4; ++i)
        out[(long)(c0 + ty + i * 8) * R + r0 + tx] = tile[tx][ty + i * 8];
}

// ---------------------------------------------------------------------------
// Row softmax on bf16 scores in place (-> probabilities bf16). fp32 math.
// Causal mask applied by index (garbage in skipped blocks never used).
// ---------------------------------------------------------------------------
__global__ __launch_bounds__(256) void softmax_bf16_kernel(
    u16* __restrict__ S, int L, int causal, long sSz)
{
    const int i = blockIdx.x;
    u16* row = S + (long)blockIdx.y * sSz + (long)i * L;
    const int t = threadIdx.x;

    const u16x8 rv = *(const u16x8*)(row + t * 8);
    float v[8];
    float m = -INFINITY;
    #pragma unroll
    for (int e = 0; e < 8; ++e) {
        const int j = t * 8 + e;
        float val = (causal && j > i) ? -INFINITY : bf2f(rv[e]);
        v[e] = val;
        m = fmaxf(m, val);
    }
    #pragma unroll
    for (int o = 32; o > 0; o >>= 1) m = fmaxf(m, __shfl_down(m, o, 64));
    __shared__ float redm[4];
    if ((t & 63) == 0) redm[t >> 6] = m;
    __syncthreads();
    m = fmaxf(fmaxf(redm[0], redm[1]), fmaxf(redm[2], redm[3]));

    float sum = 0.f;
    #pragma unroll
    for (int e = 0; e < 8; ++e) { float ex = expf(v[e] - m); v[e] = ex; sum += ex; }
    #pragma unroll
    for (int o = 32; o > 0; o >>= 1) sum += __shfl_down(sum, o, 64);
    __shared__ float reds[4];
    if ((t & 63) == 0) reds[t >> 6] = sum;
    __syncthreads();
    sum = reds[0] + reds[1] + reds[2] + reds[3];

    const float inv = 1.0f / sum;
    u16x8 ov;
    #pragma unroll
    for (int e = 0; e < 8; ++e) ov[e] = f2bf(v[e] * inv);
    *(u16x8*)(row + t * 8) = ov;
}

// ---------------------------------------------------------------------------
// out = LayerNorm(x + y; gamma, beta, eps=1e-3), D=1024; optional bf16 copy.
// ---------------------------------------------------------------------------
__global__ __launch_bounds__(256) void add_ln_kernel(
    const float* __restrict__ X, const float* __restrict__ Y,
    const float* __restrict__ gamma, const float* __restrict__ beta,
    float* __restrict__ out, u16* __restrict__ outb, int D)
{
    const long r = blockIdx.x;
    const int t = threadIdx.x;
    const float4 x = *(const float4*)&X[r * D + t * 4];
    const float4 y = *(const float4*)&Y[r * D + t * 4];
    float s0 = x.x + y.x, s1 = x.y + y.y, s2 = x.z + y.z, s3 = x.w + y.w;

    float sum = s0 + s1 + s2 + s3;
    float sq  = s0 * s0 + s1 * s1 + s2 * s2 + s3 * s3;
    #pragma unroll
    for (int o = 32; o > 0; o >>= 1) {
        sum += __shfl_down(sum, o, 64);
        sq  += __shfl_down(sq, o, 64);
    }
    __shared__ float rsum[4], rsq[4];
    if ((t & 63) == 0) { rsum[t >> 6] = sum; rsq[t >> 6] = sq; }
    __syncthreads();
    sum = rsum[0] + rsum[1] + rsum[2] + rsum[3];
    sq  = rsq[0] + rsq[1] + rsq[2] + rsq[3];

    const float mu   = sum / (float)D;
    const float var  = sq / (float)D - mu * mu;
    const float rstd = rsqrtf(var + 1e-3f);

    const float4 g = *(const float4*)&gamma[t * 4];
    const float4 b = *(const float4*)&beta[t * 4];
    float4 o;
    o.x = (s0 - mu) * rstd * g.x + b.x;
    o.y = (s1 - mu) * rstd * g.y + b.y;
    o.z = (s2 - mu) * rstd * g.z + b.z;
    o.w = (s3 - mu) * rstd * g.w + b.w;
    *(float4*)&out[r * D + t * 4] = o;
    if (outb) {
        u16x4 ob;
        ob[0] = f2bf(o.x); ob[1] = f2bf(o.y); ob[2] = f2bf(o.z); ob[3] = f2bf(o.w);
        *(u16x4*)&outb[r * D + t * 4] = ob;
    }
}

// ---------------------------------------------------------------------------
extern "C" void kernel_launch(void* const* d_in, const int* in_sizes, int n_in,
                              void* d_out, int out_size, void* d_ws, size_t ws_size,
                              hipStream_t stream)
{
    const int B = BB, L = LL_, D = DD, H = HH;
    const long LD  = (long)L * D;        // 2M elems
    const long LLs = (long)L * L;        // 4M elems
    const long BLD = (long)B * LD;       // 16.78M elems
    const int  BL  = B * L;              // 16384

    const float* x     = (const float*)d_in[0];
    const float* ctx   = (const float*)d_in[1];
    const float* Wk_s  = (const float*)d_in[2];
    const float* Wv_s  = (const float*)d_in[3];
    const float* Wq_s  = (const float*)d_in[4];
    const float* Wk_c  = (const float*)d_in[5];
    const float* Wv_c  = (const float*)d_in[6];
    const float* Wq_c  = (const float*)d_in[7];
    const float* W1    = (const float*)d_in[8];
    const float* b1    = (const float*)d_in[9];
    const float* W2    = (const float*)d_in[10];
    const float* b2    = (const float*)d_in[11];
    const float* gamma = (const float*)d_in[12];
    const float* beta  = (const float*)d_in[13];
    float* out = (float*)d_out;

    // ---- workspace layout (bump allocator) ----
    size_t ofs = 0;
    auto alloc = [&](size_t bytes) -> char* {
        char* p = (char*)d_ws + ofs;
        ofs += (bytes + 255) & ~(size_t)255;
        return p;
    };
    u16* WkTs = (u16*)alloc((size_t)D * D * 2);
    u16* WvTs = (u16*)alloc((size_t)D * D * 2);
    u16* WqTs = (u16*)alloc((size_t)D * D * 2);
    u16* WkTc = (u16*)alloc((size_t)D * D * 2);
    u16* WvTc = (u16*)alloc((size_t)D * D * 2);
    u16* WqTc = (u16*)alloc((size_t)D * D * 2);
    u16* W1T  = (u16*)alloc((size_t)D * H * 2);   // [H][D]
    u16* W2T  = (u16*)alloc((size_t)H * D * 2);   // [D][H]
    u16* actb1 = (u16*)alloc((size_t)BLD * 2);    // xb -> ctxb -> o2b
    u16* actb2 = (u16*)alloc((size_t)BLD * 2);    // o1b
    float* o2  = (float*)alloc((size_t)BLD * 4);
    char* scratch = (char*)d_ws + ofs;
    const size_t remain = ws_size > ofs ? ws_size - ofs : 0;

    // attention batch-group scratch: q,k,v,vt (bf16 LD each) + P (bf16 LLs)
    // + attn (fp32 LD) per batch
    const size_t per_b = (size_t)(4 * LD + LLs) * 2 + (size_t)LD * 4;
    long gl = (long)(remain / per_b);
    const int g = gl < 1 ? 1 : (gl > B ? B : (int)gl);

    u16* qb  = (u16*)scratch;
    u16* kb  = qb + (size_t)g * LD;
    u16* vb  = kb + (size_t)g * LD;
    u16* vtb = vb + (size_t)g * LD;
    u16* Pb  = vtb + (size_t)g * LD;
    float* attnb = (float*)(Pb + (size_t)g * LLs);

    const float scale = 1.0f / sqrtf((float)L);
    const dim3 blk(256);
    const dim3 blk512(512);

    // ---- weight transposes (fp32 -> bf16, [K][N] -> [N][K]) ----
    transpose_f2b_kernel<<<dim3(D/32, D/32), blk, 0, stream>>>(Wk_s, WkTs, D, D);
    transpose_f2b_kernel<<<dim3(D/32, D/32), blk, 0, stream>>>(Wv_s, WvTs, D, D);
    transpose_f2b_kernel<<<dim3(D/32, D/32), blk, 0, stream>>>(Wq_s, WqTs, D, D);
    transpose_f2b_kernel<<<dim3(D/32, D/32), blk, 0, stream>>>(Wk_c, WkTc, D, D);
    transpose_f2b_kernel<<<dim3(D/32, D/32), blk, 0, stream>>>(Wv_c, WvTc, D, D);
    transpose_f2b_kernel<<<dim3(D/32, D/32), blk, 0, stream>>>(Wq_c, WqTc, D, D);
    transpose_f2b_kernel<<<dim3(H/32, D/32), blk, 0, stream>>>(W1, W1T, D, H);
    transpose_f2b_kernel<<<dim3(D/32, H/32), blk, 0, stream>>>(W2, W2T, H, D);

    // attention phase: per batch-group proj + scores + softmax + PV + add/LN
    auto attn_phase = [&](const u16* qsrcb, const u16* kvsrcb,
                          const u16* WqT, const u16* WkT, const u16* WvT,
                          const float* resid, float* dst, u16* dstb, int causal) {
        for (int b0 = 0; b0 < B; b0 += g) {
            const int gb = (B - b0) < g ? (B - b0) : g;
            const long off = (long)b0 * LD;
            gemm256_kernel<u16, false, false, false, false>
                <<<dim3(D/256, gb*L/256), blk512, 0, stream>>>(
                    qsrcb + off, WqT, nullptr, qb, D, D, 1.f, 0, 0, 0);
            gemm256_kernel<u16, false, false, false, false>
                <<<dim3(D/256, gb*L/256), blk512, 0, stream>>>(
                    kvsrcb + off, WkT, nullptr, kb, D, D, 1.f, 0, 0, 0);
            gemm256_kernel<u16, false, false, false, false>
                <<<dim3(D/256, gb*L/256), blk512, 0, stream>>>(
                    kvsrcb + off, WvT, nullptr, vb, D, D, 1.f, 0, 0, 0);
            transpose_b2b_kernel<<<dim3(D/32, L/32, gb), blk, 0, stream>>>(
                vb, vtb, L, D, LD, LD);
            if (causal) {
                gemm256_kernel<u16, false, false, true, false>
                    <<<dim3(L/256, L/256, gb), blk512, 0, stream>>>(
                        qb, kb, nullptr, Pb, D, L, scale, LD, LD, LLs);
            } else {
                gemm256_kernel<u16, false, false, false, false>
                    <<<dim3(L/256, L/256, gb), blk512, 0, stream>>>(
                        qb, kb, nullptr, Pb, D, L, scale, LD, LD, LLs);
            }
            softmax_bf16_kernel<<<dim3(L, gb), blk, 0, stream>>>(Pb, L, causal, LLs);
            if (causal) {
                gemm256_kernel<float, false, false, false, true>
                    <<<dim3(D/256, L/256, gb), blk512, 0, stream>>>(
                        Pb, vtb, nullptr, attnb, L, D, 1.f, LLs, LD, LD);
            } else {
                gemm256_kernel<float, false, false, false, false>
                    <<<dim3(D/256, L/256, gb), blk512, 0, stream>>>(
                        Pb, vtb, nullptr, attnb, L, D, 1.f, LLs, LD, LD);
            }
            add_ln_kernel<<<dim3(gb * L), blk, 0, stream>>>(
                resid + off, attnb, gamma, beta, dst + off,
                dstb ? dstb + off : nullptr, D);
        }
    };

    // ---- Phase A: self-attention (causal). o1 fp32 -> d_out, o1b -> actb2 ----
    f2b_kernel<<<dim3(BLD / 2048), blk, 0, stream>>>(x, actb1);       // xb
    attn_phase(actb1, actb1, WqTs, WkTs, WvTs, x, out, actb2, 1);

    // ---- Phase B: cross-attention. o2 fp32 -> ws, o2b -> actb1 ----
    f2b_kernel<<<dim3(BLD / 2048), blk, 0, stream>>>(ctx, actb1);     // ctxb
    // o2b overwrites actb1 rows only after that group's k/v are consumed.
    attn_phase(actb2, actb1, WqTc, WkTc, WvTc, out, o2, actb1, 0);

    // ---- Phase C: FFN + LN, row-chunked through scratch ----
    {
        long mc = (long)(remain / ((size_t)H * 2 + (size_t)D * 4));
        mc = (mc / 256) * 256;
        if (mc > BL) mc = BL;
        if (mc < 256) mc = 256;
        for (long m0 = 0; m0 < BL; m0 += mc) {
            const long rows = (BL - m0) < mc ? (BL - m0) : mc;
            u16* h = (u16*)scratch;                          // [rows, H] bf16
            float* ff = (float*)(scratch + (size_t)rows * H * 2);  // [rows, D]
            gemm256_kernel<u16, true, true, false, false>
                <<<dim3(H/256, rows/256), blk512, 0, stream>>>(
                    actb1 + m0 * D, W1T, b1, h, D, H, 1.f, 0, 0, 0);
            gemm256_kernel<float, true, false, false, false>
                <<<dim3(D/256, rows/256), blk512, 0, stream>>>(
                    h, W2T, b2, ff, H, D, 1.f, 0, 0, 0);
            add_ln_kernel<<<dim3(rows), blk, 0, stream>>>(
                o2 + m0 * D, ff, gamma, beta, out + m0 * D, nullptr, D);
        }
    }
}

// Round 8
// 1324.327 us; speedup vs baseline: 1.2353x; 1.1395x over previous
//
#include <hip/hip_runtime.h>
#include <math.h>

// Problem dims (fixed by reference setup_inputs)
#define BB 8
#define LL_ 2048
#define DD 1024
#define HH 2048

typedef unsigned short u16;
typedef __attribute__((ext_vector_type(8))) u16 u16x8;
typedef __attribute__((ext_vector_type(4))) u16 u16x4;
typedef __attribute__((ext_vector_type(8))) __bf16 bf16x8;
typedef __attribute__((ext_vector_type(4))) float f32x4;

__device__ __forceinline__ u16 f2bf(float f) {
    union { float f; unsigned u; } v; v.f = f;
    unsigned r = (v.u + 0x7FFFu + ((v.u >> 16) & 1u)) >> 16;
    return (u16)r;
}
__device__ __forceinline__ float bf2f(u16 h) {
    union { unsigned u; float f; } v; v.u = ((unsigned)h) << 16;
    return v.f;
}

// async global->LDS, 16 bytes per lane (global_load_lds_dwordx4)
__device__ __forceinline__ void gload16(const u16* g, u16* l) {
    __builtin_amdgcn_global_load_lds(
        (const __attribute__((address_space(1))) unsigned*)g,
        (__attribute__((address_space(3))) unsigned*)l, 16, 0, 0);
}

// MFMA quadrant: 4m x 2n frags x 2 ksub = 16 MFMA, constexpr acc indices.
template <int MH, int NH>
__device__ __forceinline__ void quad(f32x4 (&acc)[8][4],
                                     const bf16x8 (&aF)[4][2],
                                     const bf16x8 (&bF)[2][2]) {
    #pragma unroll
    for (int mq = 0; mq < 4; ++mq)
        #pragma unroll
        for (int nq = 0; nq < 2; ++nq)
            #pragma unroll
            for (int ks = 0; ks < 2; ++ks)
                acc[MH * 4 + mq][NH * 2 + nq] =
                    __builtin_amdgcn_mfma_f32_16x16x32_bf16(
                        aF[mq][ks], bF[nq][ks], acc[MH * 4 + mq][NH * 2 + nq],
                        0, 0, 0);
}

// ---------------------------------------------------------------------------
// 256x256 8-phase bf16 MFMA GEMM, NT form: C[M,N] = A[M,K] @ Bt[N,K]^T with
// row strides lda/ldb/ldc (enables fused-QKV slices).  512 threads = 8 waves
// (2x4); wave tile 128x64 = 8x4 frags of 16x16x32.  BK=64 K-tiles, double-
// buffered 128 KiB LDS, half-tile staging via global_load_lds with inverse-
// swizzled source; ds_read swizzle byte ^= ((row&7)<<4) -> conflict-free.
// Counted vmcnt(4) at phases 4/8 only.  STG never skips (source clamped to
// nt-1, dead dest slot) so the vmcnt ledger is uniform.  Chunked XCD swizzle
// (bijective when nwg%8==0) for L2 panel locality.
// CSKIP: skip blocks fully above causal diagonal.  CKEND: kend=i0+256 (P@V).
// ---------------------------------------------------------------------------
template <typename OutT, bool BIAS, bool RELU, bool CSKIP, bool CKEND>
__global__ __launch_bounds__(512, 2) void gemm256_kernel(
    const u16* __restrict__ A, const u16* __restrict__ Bt,
    const float* __restrict__ bias, OutT* __restrict__ C,
    int K, int N, float scale, int lda, int ldb, int ldc,
    long sAz, long sBz, long sCz)
{
    // chunked XCD swizzle: same-XCD blocks get contiguous linear ids
    int bx = blockIdx.x, by = blockIdx.y;
    {
        const int nwg = gridDim.x * gridDim.y;
        if ((nwg & 7) == 0) {
            int bid = by * gridDim.x + bx;
            bid = (bid & 7) * (nwg >> 3) + (bid >> 3);
            bx = bid % gridDim.x;
            by = bid / gridDim.x;
        }
    }
    const int i0 = by * 256;   // M block
    const int n0 = bx * 256;   // N block
    if (CSKIP && n0 > i0 + 255) return;

    A  += (long)blockIdx.z * sAz;
    Bt += (long)blockIdx.z * sBz;
    C  += (long)blockIdx.z * sCz;

    // 2 bufs x (A: 2 halves + B: 2 halves) x 16 KiB = 128 KiB
    __shared__ u16 lds[65536];

    int kend = K;
    if (CKEND) { int ke = i0 + 256; kend = ke < K ? ke : K; }
    const int nt = kend >> 6;          // K-tiles of 64 (even, >=4 here)

    const int t   = threadIdx.x;
    const int wid = t >> 6, l = t & 63;
    const int wr  = wid >> 2, wc = wid & 3;   // 2x4 wave grid
    const int lg  = l >> 4,  lr = l & 15;

    // staging: thread t -> half-tile row srow(+64), logical k-chunk sch
    // (inverse swizzle so linear LDS dest yields swizzled layout)
    const int srow = t >> 3;                    // 0..63
    const int sch  = (t & 7) ^ (srow & 7);      // logical 8-elem chunk

    // swizzled read slots (u16 units): chunk c at byte (c ^ (row&7))*16
    const int slot0 = ((lg) ^ (lr & 7)) * 8;        // ksub=0, chunk=lg
    const int slot1 = ((4 + lg) ^ (lr & 7)) * 8;    // ksub=1, chunk=4+lg

    f32x4 acc[8][4];
    #pragma unroll
    for (int m = 0; m < 8; ++m)
        #pragma unroll
        for (int n = 0; n < 4; ++n)
            acc[m][n] = (f32x4){0.f, 0.f, 0.f, 0.f};

    bf16x8 aF[4][2], bF0[2][2], bF1[2][2];

    auto readA_f = [&](int bufb, int mh) {
        const u16* base = lds + bufb + wr * 8192 + mh * 4096 + lr * 64;
        #pragma unroll
        for (int mq = 0; mq < 4; ++mq) {
            aF[mq][0] = *(const bf16x8*)(base + mq * 1024 + slot0);
            aF[mq][1] = *(const bf16x8*)(base + mq * 1024 + slot1);
        }
    };
    auto readB_f = [&](int bufb, int nh, bf16x8 (&bf)[2][2]) {
        const u16* base = lds + bufb + 16384 + (wc >> 1) * 8192 +
                          (wc & 1) * 4096 + nh * 2048 + lr * 64;
        #pragma unroll
        for (int nq = 0; nq < 2; ++nq) {
            bf[nq][0] = *(const bf16x8*)(base + nq * 1024 + slot0);
            bf[nq][1] = *(const bf16x8*)(base + nq * 1024 + slot1);
        }
    };
    // which: 0=A-half0, 1=A-half1, 2=B-half0, 3=B-half1.
    // Source tile clamped to nt-1 (dest slot from ORIGINAL tile parity is
    // dead when tile >= nt) so the vmcnt ledger stays uniform.
    auto STG = [&](int tile, int which) {
        const int  st  = tile < nt ? tile : nt - 1;
        const bool isB = which >= 2;
        const int  h   = which & 1;
        const u16* src = isB ? Bt : A;
        const int  ld  = isB ? ldb : lda;
        const int  r0  = (isB ? n0 : i0) + h * 128 + srow;
        const long g   = (long)r0 * ld + st * 64 + sch * 8;
        u16* d = lds + (tile & 1) * 32768 + (isB ? 16384 : 0) + h * 8192 + t * 8;
        gload16(src + g, d);
        gload16(src + g + (long)64 * ld, d + 4096);
    };

#define PHASE(MH, NH, RA, RB, BF, BUFB, STILE, SWHICH, VM4)                 \
    {                                                                       \
        if (RA) readA_f(BUFB, MH);                                          \
        if (RB) readB_f(BUFB, NH, BF);                                      \
        STG(STILE, SWHICH);                                                 \
        if (VM4) asm volatile("s_waitcnt vmcnt(4)" ::: "memory");           \
        asm volatile("s_barrier" ::: "memory");                             \
        __builtin_amdgcn_s_setprio(1);                                      \
        quad<MH, NH>(acc, aF, BF);                                          \
        __builtin_amdgcn_s_setprio(0);                                      \
        asm volatile("s_barrier" ::: "memory");                             \
    }

    // prologue: T0 {B0,B1,A0,A1}, T1 {B0,B1}; wait all but newest 2 halves
    STG(0, 2); STG(0, 3); STG(0, 0); STG(0, 1);
    STG(1, 2); STG(1, 3);
    asm volatile("s_waitcnt vmcnt(4)" ::: "memory");
    asm volatile("s_barrier" ::: "memory");

    for (int j = 0; j < nt; j += 2) {
        // K-tile j in buf0 (phases 1-4), j+1 in buf1 (phases 5-8)
        PHASE(0, 0, 1, 1, bF0, 0,     j + 1, 0, 0)   // stage A0(j+1)
        PHASE(0, 1, 0, 1, bF1, 0,     j + 1, 1, 0)   // stage A1(j+1)
        PHASE(1, 1, 1, 0, bF1, 0,     j + 2, 2, 0)   // stage B0(j+2)
        PHASE(1, 0, 0, 0, bF0, 0,     j + 2, 3, 1)   // stage B1(j+2), vmcnt(4)
        PHASE(0, 0, 1, 1, bF0, 32768, j + 2, 0, 0)   // stage A0(j+2)
        PHASE(0, 1, 0, 1, bF1, 32768, j + 2, 1, 0)   // stage A1(j+2)
        PHASE(1, 1, 1, 0, bF1, 32768, j + 3, 2, 0)   // stage B0(j+3)
        PHASE(1, 0, 0, 0, bF0, 32768, j + 3, 3, 1)   // stage B1(j+3), vmcnt(4)
    }
#undef PHASE

    // drain in-flight LDS-DMA (dead-slot stages) before epilogue / endpgm
    asm volatile("s_waitcnt vmcnt(0)" ::: "memory");

    // epilogue: C frag mapping col = lane&15, row = (lane>>4)*4 + r
    #pragma unroll
    for (int nj = 0; nj < 4; ++nj) {
        const int col = n0 + wc * 64 + nj * 16 + lr;
        const float bv = BIAS ? bias[col] : 0.f;
        #pragma unroll
        for (int mi = 0; mi < 8; ++mi) {
            const int row0 = i0 + wr * 128 + mi * 16 + lg * 4;
            #pragma unroll
            for (int r = 0; r < 4; ++r) {
                float val = acc[mi][nj][r] * scale + bv;
                if (RELU) val = fmaxf(val, 0.f);
                if (sizeof(OutT) == 4) {
                    ((float*)C)[(long)(row0 + r) * ldc + col] = val;
                } else {
                    ((u16*)C)[(long)(row0 + r) * ldc + col] = f2bf(val);
                }
            }
        }
    }
}

// ---------------------------------------------------------------------------
// fp32 -> bf16 elementwise convert (n multiple of 2048)
// ---------------------------------------------------------------------------
__global__ __launch_bounds__(256) void f2b_kernel(
    const float* __restrict__ in, u16* __restrict__ out)
{
    const long i = ((long)blockIdx.x * 256 + threadIdx.x) * 8;
    const float4 a = *(const float4*)(in + i);
    const float4 b = *(const float4*)(in + i + 4);
    u16x8 o;
    o[0] = f2bf(a.x); o[1] = f2bf(a.y); o[2] = f2bf(a.z); o[3] = f2bf(a.w);
    o[4] = f2bf(b.x); o[5] = f2bf(b.y); o[6] = f2bf(b.z); o[7] = f2bf(b.w);
    *(u16x8*)(out + i) = o;
}

// ---------------------------------------------------------------------------
// transpose fp32 [R][C] -> bf16 [C][R]  (weights; R,C multiples of 32)
// ---------------------------------------------------------------------------
__global__ __launch_bounds__(256) void transpose_f2b_kernel(
    const float* __restrict__ in, u16* __restrict__ out, int R, int C)
{
    __shared__ float tile[32][33];
    const int tx = threadIdx.x & 31, ty = threadIdx.x >> 5;
    const int c0 = blockIdx.x * 32, r0 = blockIdx.y * 32;
    #pragma unroll
    for (int i = 0; i < 4; ++i)
        tile[ty + i * 8][tx] = in[(long)(r0 + ty + i * 8) * C + c0 + tx];
    __syncthreads();
    #pragma unroll
    for (int i = 0; i < 4; ++i)
        out[(long)(c0 + ty + i * 8) * R + r0 + tx] = f2bf(tile[tx][ty + i * 8]);
}

// ---------------------------------------------------------------------------
// transpose bf16 [R][C] (row stride lda) -> bf16 [C][R], z-batched (V^T)
// ---------------------------------------------------------------------------
__global__ __launch_bounds__(256) void transpose_b2b_kernel(
    const u16* __restrict__ in, u16* __restrict__ out, int lda, int R, int C,
    long sIz, long sOz)
{
    __shared__ u16 tile[32][33];
    in  += (long)blockIdx.z * sIz;
    out += (long)blockIdx.z * sOz;
    const int tx = threadIdx.x & 31, ty = threadIdx.x >> 5;
    const int c0 = blockIdx.x * 32, r0 = blockIdx.y * 32;
    #pragma unroll
    for (int i = 0; i < 4; ++i)
        tile[ty + i * 8][tx] = in[(long)(r0 + ty + i * 8) * lda + c0 + tx];
    __syncthreads();
    #pragma unroll
    for (int i = 0; i < 4; ++i)
        out[(long)(c0 + ty + i * 8) * R + r0 + tx] = tile[tx][ty + i * 8];
}

// ---------------------------------------------------------------------------
// Row softmax on bf16 scores in place (-> probabilities bf16). fp32 math.
// Causal mask applied by index (garbage in skipped blocks never used).
// ---------------------------------------------------------------------------
__global__ __launch_bounds__(256) void softmax_bf16_kernel(
    u16* __restrict__ S, int L, int causal, long sSz)
{
    const int i = blockIdx.x;
    u16* row = S + (long)blockIdx.y * sSz + (long)i * L;
    const int t = threadIdx.x;

    const u16x8 rv = *(const u16x8*)(row + t * 8);
    float v[8];
    float m = -INFINITY;
    #pragma unroll
    for (int e = 0; e < 8; ++e) {
        const int j = t * 8 + e;
        float val = (causal && j > i) ? -INFINITY : bf2f(rv[e]);
        v[e] = val;
        m = fmaxf(m, val);
    }
    #pragma unroll
    for (int o = 32; o > 0; o >>= 1) m = fmaxf(m, __shfl_down(m, o, 64));
    __shared__ float redm[4];
    if ((t & 63) == 0) redm[t >> 6] = m;
    __syncthreads();
    m = fmaxf(fmaxf(redm[0], redm[1]), fmaxf(redm[2], redm[3]));

    float sum = 0.f;
    #pragma unroll
    for (int e = 0; e < 8; ++e) { float ex = expf(v[e] - m); v[e] = ex; sum += ex; }
    #pragma unroll
    for (int o = 32; o > 0; o >>= 1) sum += __shfl_down(sum, o, 64);
    __shared__ float reds[4];
    if ((t & 63) == 0) reds[t >> 6] = sum;
    __syncthreads();
    sum = reds[0] + reds[1] + reds[2] + reds[3];

    const float inv = 1.0f / sum;
    u16x8 ov;
    #pragma unroll
    for (int e = 0; e < 8; ++e) ov[e] = f2bf(v[e] * inv);
    *(u16x8*)(row + t * 8) = ov;
}

// ---------------------------------------------------------------------------
// out = LayerNorm(x + y; gamma, beta, eps=1e-3), D=1024; optional bf16 copy.
// ---------------------------------------------------------------------------
__global__ __launch_bounds__(256) void add_ln_kernel(
    const float* __restrict__ X, const float* __restrict__ Y,
    const float* __restrict__ gamma, const float* __restrict__ beta,
    float* __restrict__ out, u16* __restrict__ outb, int D)
{
    const long r = blockIdx.x;
    const int t = threadIdx.x;
    const float4 x = *(const float4*)&X[r * D + t * 4];
    const float4 y = *(const float4*)&Y[r * D + t * 4];
    float s0 = x.x + y.x, s1 = x.y + y.y, s2 = x.z + y.z, s3 = x.w + y.w;

    float sum = s0 + s1 + s2 + s3;
    float sq  = s0 * s0 + s1 * s1 + s2 * s2 + s3 * s3;
    #pragma unroll
    for (int o = 32; o > 0; o >>= 1) {
        sum += __shfl_down(sum, o, 64);
        sq  += __shfl_down(sq, o, 64);
    }
    __shared__ float rsum[4], rsq[4];
    if ((t & 63) == 0) { rsum[t >> 6] = sum; rsq[t >> 6] = sq; }
    __syncthreads();
    sum = rsum[0] + rsum[1] + rsum[2] + rsum[3];
    sq  = rsq[0] + rsq[1] + rsq[2] + rsq[3];

    const float mu   = sum / (float)D;
    const float var  = sq / (float)D - mu * mu;
    const float rstd = rsqrtf(var + 1e-3f);

    const float4 g = *(const float4*)&gamma[t * 4];
    const float4 b = *(const float4*)&beta[t * 4];
    float4 o;
    o.x = (s0 - mu) * rstd * g.x + b.x;
    o.y = (s1 - mu) * rstd * g.y + b.y;
    o.z = (s2 - mu) * rstd * g.z + b.z;
    o.w = (s3 - mu) * rstd * g.w + b.w;
    *(float4*)&out[r * D + t * 4] = o;
    if (outb) {
        u16x4 ob;
        ob[0] = f2bf(o.x); ob[1] = f2bf(o.y); ob[2] = f2bf(o.z); ob[3] = f2bf(o.w);
        *(u16x4*)&outb[r * D + t * 4] = ob;
    }
}

// ---------------------------------------------------------------------------
extern "C" void kernel_launch(void* const* d_in, const int* in_sizes, int n_in,
                              void* d_out, int out_size, void* d_ws, size_t ws_size,
                              hipStream_t stream)
{
    const int B = BB, L = LL_, D = DD, H = HH;
    const long LD  = (long)L * D;        // 2M elems
    const long LLs = (long)L * L;        // 4M elems
    const long BLD = (long)B * LD;       // 16.78M elems
    const int  BL  = B * L;              // 16384
    const int  D3  = 3 * D;              // fused QKV width

    const float* x     = (const float*)d_in[0];
    const float* ctx   = (const float*)d_in[1];
    const float* Wk_s  = (const float*)d_in[2];
    const float* Wv_s  = (const float*)d_in[3];
    const float* Wq_s  = (const float*)d_in[4];
    const float* Wk_c  = (const float*)d_in[5];
    const float* Wv_c  = (const float*)d_in[6];
    const float* Wq_c  = (const float*)d_in[7];
    const float* W1    = (const float*)d_in[8];
    const float* b1    = (const float*)d_in[9];
    const float* W2    = (const float*)d_in[10];
    const float* b2    = (const float*)d_in[11];
    const float* gamma = (const float*)d_in[12];
    const float* beta  = (const float*)d_in[13];
    float* out = (float*)d_out;

    // ---- workspace layout (bump allocator) ----
    size_t ofs = 0;
    auto alloc = [&](size_t bytes) -> char* {
        char* p = (char*)d_ws + ofs;
        ofs += (bytes + 255) & ~(size_t)255;
        return p;
    };
    u16* WqkvTs = (u16*)alloc((size_t)3 * D * D * 2);  // [3D][D]: Q,K,V slices
    u16* WqTc   = (u16*)alloc((size_t)D * D * 2);      // [D][D]
    u16* WkvTc  = (u16*)alloc((size_t)2 * D * D * 2);  // [2D][D]: K,V slices
    u16* W1T  = (u16*)alloc((size_t)D * H * 2);        // [H][D]
    u16* W2T  = (u16*)alloc((size_t)H * D * 2);        // [D][H]
    u16* actb1 = (u16*)alloc((size_t)BLD * 2);    // xb -> ctxb -> o2b
    u16* actb2 = (u16*)alloc((size_t)BLD * 2);    // o1b
    float* o2  = (float*)alloc((size_t)BLD * 4);
    char* scratch = (char*)d_ws + ofs;
    const size_t remain = ws_size > ofs ? ws_size - ofs : 0;

    // per-batch attention scratch: qkv [L][3D] bf16 + vt [D][L] bf16
    // + P [L][L] bf16 + attn [L][D] fp32
    const size_t per_b = (size_t)(3 * LD + LD + LLs) * 2 + (size_t)LD * 4;
    long gl = (long)(remain / per_b);
    const int g = gl < 1 ? 1 : (gl > B ? B : (int)gl);

    u16* qkvb = (u16*)scratch;                       // [g*L][3D]
    u16* vtb  = qkvb + (size_t)g * L * D3;           // [g][D][L]
    u16* Pb   = vtb + (size_t)g * LD;                // [g][L][L]
    float* attnb = (float*)(Pb + (size_t)g * LLs);   // [g][L][D]

    const float scale = 1.0f / sqrtf((float)L);
    const dim3 blk(256);
    const dim3 blk512(512);
    const long L3D = (long)L * D3;

    // ---- weight transposes (fp32 -> bf16, [K][N] -> [N][K], into slices) ----
    transpose_f2b_kernel<<<dim3(D/32, D/32), blk, 0, stream>>>(Wq_s, WqkvTs,           D, D);
    transpose_f2b_kernel<<<dim3(D/32, D/32), blk, 0, stream>>>(Wk_s, WqkvTs + (size_t)D*D,   D, D);
    transpose_f2b_kernel<<<dim3(D/32, D/32), blk, 0, stream>>>(Wv_s, WqkvTs + (size_t)2*D*D, D, D);
    transpose_f2b_kernel<<<dim3(D/32, D/32), blk, 0, stream>>>(Wq_c, WqTc, D, D);
    transpose_f2b_kernel<<<dim3(D/32, D/32), blk, 0, stream>>>(Wk_c, WkvTc,            D, D);
    transpose_f2b_kernel<<<dim3(D/32, D/32), blk, 0, stream>>>(Wv_c, WkvTc + (size_t)D*D,   D, D);
    transpose_f2b_kernel<<<dim3(H/32, D/32), blk, 0, stream>>>(W1, W1T, D, H);
    transpose_f2b_kernel<<<dim3(D/32, H/32), blk, 0, stream>>>(W2, W2T, H, D);

    // attention tail (shared): V^T, scores, softmax, PV, add+LN
    auto attn_tail = [&](int gb, long off, const float* resid, float* dst,
                         u16* dstb, int causal) {
        transpose_b2b_kernel<<<dim3(D/32, L/32, gb), blk, 0, stream>>>(
            qkvb + 2 * D, vtb, D3, L, D, L3D, LD);
        if (causal) {
            gemm256_kernel<u16, false, false, true, false>
                <<<dim3(L/256, L/256, gb), blk512, 0, stream>>>(
                    qkvb, qkvb + D, nullptr, Pb, D, L, scale,
                    D3, D3, L, L3D, L3D, LLs);
        } else {
            gemm256_kernel<u16, false, false, false, false>
                <<<dim3(L/256, L/256, gb), blk512, 0, stream>>>(
                    qkvb, qkvb + D, nullptr, Pb, D, L, scale,
                    D3, D3, L, L3D, L3D, LLs);
        }
        softmax_bf16_kernel<<<dim3(L, gb), blk, 0, stream>>>(Pb, L, causal, LLs);
        if (causal) {
            gemm256_kernel<float, false, false, false, true>
                <<<dim3(D/256, L/256, gb), blk512, 0, stream>>>(
                    Pb, vtb, nullptr, attnb, L, D, 1.f,
                    L, L, D, LLs, LD, LD);
        } else {
            gemm256_kernel<float, false, false, false, false>
                <<<dim3(D/256, L/256, gb), blk512, 0, stream>>>(
                    Pb, vtb, nullptr, attnb, L, D, 1.f,
                    L, L, D, LLs, LD, LD);
        }
        add_ln_kernel<<<dim3(gb * L), blk, 0, stream>>>(
            resid + off, attnb, gamma, beta, dst + off,
            dstb ? dstb + off : nullptr, D);
    };

    // ---- Phase A: self-attention (causal). o1 fp32 -> d_out, o1b -> actb2 ----
    f2b_kernel<<<dim3(BLD / 2048), blk, 0, stream>>>(x, actb1);       // xb
    for (int b0 = 0; b0 < B; b0 += g) {
        const int gb = (B - b0) < g ? (B - b0) : g;
        const long off = (long)b0 * LD;
        // fused QKV projection: [gb*L, D] x [D, 3D]
        gemm256_kernel<u16, false, false, false, false>
            <<<dim3(D3/256, gb*L/256), blk512, 0, stream>>>(
                actb1 + off, WqkvTs, nullptr, qkvb, D, D3, 1.f,
                D, D, D3, 0, 0, 0);
        attn_tail(gb, off, x, out, actb2, 1);
    }

    // ---- Phase B: cross-attention. o2 fp32 -> ws, o2b -> actb1 ----
    f2b_kernel<<<dim3(BLD / 2048), blk, 0, stream>>>(ctx, actb1);     // ctxb
    for (int b0 = 0; b0 < B; b0 += g) {
        const int gb = (B - b0) < g ? (B - b0) : g;
        const long off = (long)b0 * LD;
        // Q from o1b
        gemm256_kernel<u16, false, false, false, false>
            <<<dim3(D/256, gb*L/256), blk512, 0, stream>>>(
                actb2 + off, WqTc, nullptr, qkvb, D, D, 1.f,
                D, D, D3, 0, 0, 0);
        // fused KV from ctxb (o2b overwrites these rows only after consumption)
        gemm256_kernel<u16, false, false, false, false>
            <<<dim3((2*D)/256, gb*L/256), blk512, 0, stream>>>(
                actb1 + off, WkvTc, nullptr, qkvb + D, D, 2 * D, 1.f,
                D, D, D3, 0, 0, 0);
        attn_tail(gb, off, out, o2, actb1, 0);
    }

    // ---- Phase C: FFN + LN, row-chunked through scratch ----
    {
        long mc = (long)(remain / ((size_t)H * 2 + (size_t)D * 4));
        mc = (mc / 256) * 256;
        if (mc > BL) mc = BL;
        if (mc < 256) mc = 256;
        for (long m0 = 0; m0 < BL; m0 += mc) {
            const long rows = (BL - m0) < mc ? (BL - m0) : mc;
            u16* h = (u16*)scratch;                          // [rows, H] bf16
            float* ff = (float*)(scratch + (size_t)rows * H * 2);  // [rows, D]
            gemm256_kernel<u16, true, true, false, false>
                <<<dim3(H/256, rows/256), blk512, 0, stream>>>(
                    actb1 + m0 * D, W1T, b1, h, D, H, 1.f,
                    D, D, H, 0, 0, 0);
            gemm256_kernel<float, true, false, false, false>
                <<<dim3(D/256, rows/256), blk512, 0, stream>>>(
                    h, W2T, b2, ff, H, D, 1.f,
                    H, H, D, 0, 0, 0);
            add_ln_kernel<<<dim3(rows), blk, 0, stream>>>(
                o2 + m0 * D, ff, gamma, beta, out + m0 * D, nullptr, D);
        }
    }
}

// Round 9
// 1228.991 us; speedup vs baseline: 1.3311x; 1.0776x over previous
//
#include <hip/hip_runtime.h>
#include <math.h>

// Problem dims (fixed by reference setup_inputs)
#define BB 8
#define LL_ 2048
#define DD 1024
#define HH 2048

typedef unsigned short u16;
typedef __attribute__((ext_vector_type(8))) u16 u16x8;
typedef __attribute__((ext_vector_type(4))) u16 u16x4;
typedef __attribute__((ext_vector_type(8))) __bf16 bf16x8;
typedef __attribute__((ext_vector_type(4))) float f32x4;

__device__ __forceinline__ u16 f2bf(float f) {
    union { float f; unsigned u; } v; v.f = f;
    unsigned r = (v.u + 0x7FFFu + ((v.u >> 16) & 1u)) >> 16;
    return (u16)r;
}
__device__ __forceinline__ float bf2f(u16 h) {
    union { unsigned u; float f; } v; v.u = ((unsigned)h) << 16;
    return v.f;
}

// async global->LDS, 16 bytes per lane (global_load_lds_dwordx4)
__device__ __forceinline__ void gload16(const u16* g, u16* l) {
    __builtin_amdgcn_global_load_lds(
        (const __attribute__((address_space(1))) unsigned*)g,
        (__attribute__((address_space(3))) unsigned*)l, 16, 0, 0);
}

// MFMA quadrant: 4m x 2n frags x 2 ksub = 16 MFMA, constexpr acc indices.
template <int MH, int NH>
__device__ __forceinline__ void quad(f32x4 (&acc)[8][4],
                                     const bf16x8 (&aF)[4][2],
                                     const bf16x8 (&bF)[2][2]) {
    #pragma unroll
    for (int mq = 0; mq < 4; ++mq)
        #pragma unroll
        for (int nq = 0; nq < 2; ++nq)
            #pragma unroll
            for (int ks = 0; ks < 2; ++ks)
                acc[MH * 4 + mq][NH * 2 + nq] =
                    __builtin_amdgcn_mfma_f32_16x16x32_bf16(
                        aF[mq][ks], bF[nq][ks], acc[MH * 4 + mq][NH * 2 + nq],
                        0, 0, 0);
}

// ---------------------------------------------------------------------------
// 256x256 8-phase bf16 MFMA GEMM, NT form: C[M,N] = A[M,K] @ Bt[N,K]^T with
// row strides lda/ldb/ldc (enables fused-QKV slices).  512 threads = 8 waves
// (2x4); wave tile 128x64 = 8x4 frags of 16x16x32.  BK=64 K-tiles, double-
// buffered 128 KiB LDS, half-tile staging via global_load_lds with inverse-
// swizzled source; ds_read swizzle byte ^= ((row&7)<<4) -> conflict-free.
// Counted vmcnt(4) at phases 4/8 only.  STG never skips (source clamped to
// nt-1, dead dest slot) so the vmcnt ledger is uniform.  Chunked XCD swizzle
// (bijective when nwg%8==0) for L2 panel locality.
// CSKIP: skip blocks fully above causal diagonal.  CKEND: kend=i0+256 (P@V).
// ---------------------------------------------------------------------------
template <typename OutT, bool BIAS, bool RELU, bool CSKIP, bool CKEND>
__global__ __launch_bounds__(512, 2) void gemm256_kernel(
    const u16* __restrict__ A, const u16* __restrict__ Bt,
    const float* __restrict__ bias, OutT* __restrict__ C,
    int K, int N, float scale, int lda, int ldb, int ldc,
    long sAz, long sBz, long sCz)
{
    // chunked XCD swizzle: same-XCD blocks get contiguous linear ids
    int bx = blockIdx.x, by = blockIdx.y;
    {
        const int nwg = gridDim.x * gridDim.y;
        if ((nwg & 7) == 0) {
            int bid = by * gridDim.x + bx;
            bid = (bid & 7) * (nwg >> 3) + (bid >> 3);
            bx = bid % gridDim.x;
            by = bid / gridDim.x;
        }
    }
    const int i0 = by * 256;   // M block
    const int n0 = bx * 256;   // N block
    if (CSKIP && n0 > i0 + 255) return;

    A  += (long)blockIdx.z * sAz;
    Bt += (long)blockIdx.z * sBz;
    C  += (long)blockIdx.z * sCz;

    // 2 bufs x (A: 2 halves + B: 2 halves) x 16 KiB = 128 KiB
    __shared__ u16 lds[65536];

    int kend = K;
    if (CKEND) { int ke = i0 + 256; kend = ke < K ? ke : K; }
    const int nt = kend >> 6;          // K-tiles of 64 (even, >=4 here)

    const int t   = threadIdx.x;
    const int wid = t >> 6, l = t & 63;
    const int wr  = wid >> 2, wc = wid & 3;   // 2x4 wave grid
    const int lg  = l >> 4,  lr = l & 15;

    // staging: thread t -> half-tile row srow(+64), logical k-chunk sch
    // (inverse swizzle so linear LDS dest yields swizzled layout)
    const int srow = t >> 3;                    // 0..63
    const int sch  = (t & 7) ^ (srow & 7);      // logical 8-elem chunk

    // swizzled read slots (u16 units): chunk c at byte (c ^ (row&7))*16
    const int slot0 = ((lg) ^ (lr & 7)) * 8;        // ksub=0, chunk=lg
    const int slot1 = ((4 + lg) ^ (lr & 7)) * 8;    // ksub=1, chunk=4+lg

    f32x4 acc[8][4];
    #pragma unroll
    for (int m = 0; m < 8; ++m)
        #pragma unroll
        for (int n = 0; n < 4; ++n)
            acc[m][n] = (f32x4){0.f, 0.f, 0.f, 0.f};

    bf16x8 aF[4][2], bF0[2][2], bF1[2][2];

    auto readA_f = [&](int bufb, int mh) {
        const u16* base = lds + bufb + wr * 8192 + mh * 4096 + lr * 64;
        #pragma unroll
        for (int mq = 0; mq < 4; ++mq) {
            aF[mq][0] = *(const bf16x8*)(base + mq * 1024 + slot0);
            aF[mq][1] = *(const bf16x8*)(base + mq * 1024 + slot1);
        }
    };
    auto readB_f = [&](int bufb, int nh, bf16x8 (&bf)[2][2]) {
        const u16* base = lds + bufb + 16384 + (wc >> 1) * 8192 +
                          (wc & 1) * 4096 + nh * 2048 + lr * 64;
        #pragma unroll
        for (int nq = 0; nq < 2; ++nq) {
            bf[nq][0] = *(const bf16x8*)(base + nq * 1024 + slot0);
            bf[nq][1] = *(const bf16x8*)(base + nq * 1024 + slot1);
        }
    };
    // which: 0=A-half0, 1=A-half1, 2=B-half0, 3=B-half1.
    // Source tile clamped to nt-1 (dest slot from ORIGINAL tile parity is
    // dead when tile >= nt) so the vmcnt ledger stays uniform.
    auto STG = [&](int tile, int which) {
        const int  st  = tile < nt ? tile : nt - 1;
        const bool isB = which >= 2;
        const int  h   = which & 1;
        const u16* src = isB ? Bt : A;
        const int  ld  = isB ? ldb : lda;
        const int  r0  = (isB ? n0 : i0) + h * 128 + srow;
        const long g   = (long)r0 * ld + st * 64 + sch * 8;
        u16* d = lds + (tile & 1) * 32768 + (isB ? 16384 : 0) + h * 8192 + t * 8;
        gload16(src + g, d);
        gload16(src + g + (long)64 * ld, d + 4096);
    };

#define PHASE(MH, NH, RA, RB, BF, BUFB, STILE, SWHICH, VM4)                 \
    {                                                                       \
        if (RA) readA_f(BUFB, MH);                                          \
        if (RB) readB_f(BUFB, NH, BF);                                      \
        STG(STILE, SWHICH);                                                 \
        if (VM4) asm volatile("s_waitcnt vmcnt(4)" ::: "memory");           \
        asm volatile("s_barrier" ::: "memory");                             \
        __builtin_amdgcn_s_setprio(1);                                      \
        quad<MH, NH>(acc, aF, BF);                                          \
        __builtin_amdgcn_s_setprio(0);                                      \
        asm volatile("s_barrier" ::: "memory");                             \
    }

    // prologue: T0 {B0,B1,A0,A1}, T1 {B0,B1}; wait all but newest 2 halves
    STG(0, 2); STG(0, 3); STG(0, 0); STG(0, 1);
    STG(1, 2); STG(1, 3);
    asm volatile("s_waitcnt vmcnt(4)" ::: "memory");
    asm volatile("s_barrier" ::: "memory");

    for (int j = 0; j < nt; j += 2) {
        // K-tile j in buf0 (phases 1-4), j+1 in buf1 (phases 5-8)
        PHASE(0, 0, 1, 1, bF0, 0,     j + 1, 0, 0)   // stage A0(j+1)
        PHASE(0, 1, 0, 1, bF1, 0,     j + 1, 1, 0)   // stage A1(j+1)
        PHASE(1, 1, 1, 0, bF1, 0,     j + 2, 2, 0)   // stage B0(j+2)
        PHASE(1, 0, 0, 0, bF0, 0,     j + 2, 3, 1)   // stage B1(j+2), vmcnt(4)
        PHASE(0, 0, 1, 1, bF0, 32768, j + 2, 0, 0)   // stage A0(j+2)
        PHASE(0, 1, 0, 1, bF1, 32768, j + 2, 1, 0)   // stage A1(j+2)
        PHASE(1, 1, 1, 0, bF1, 32768, j + 3, 2, 0)   // stage B0(j+3)
        PHASE(1, 0, 0, 0, bF0, 32768, j + 3, 3, 1)   // stage B1(j+3), vmcnt(4)
    }
#undef PHASE

    // drain in-flight LDS-DMA (dead-slot stages) before epilogue / endpgm
    asm volatile("s_waitcnt vmcnt(0)" ::: "memory");

    // epilogue: C frag mapping col = lane&15, row = (lane>>4)*4 + r
    #pragma unroll
    for (int nj = 0; nj < 4; ++nj) {
        const int col = n0 + wc * 64 + nj * 16 + lr;
        const float bv = BIAS ? bias[col] : 0.f;
        #pragma unroll
        for (int mi = 0; mi < 8; ++mi) {
            const int row0 = i0 + wr * 128 + mi * 16 + lg * 4;
            #pragma unroll
            for (int r = 0; r < 4; ++r) {
                float val = acc[mi][nj][r] * scale + bv;
                if (RELU) val = fmaxf(val, 0.f);
                if (sizeof(OutT) == 4) {
                    ((float*)C)[(long)(row0 + r) * ldc + col] = val;
                } else {
                    ((u16*)C)[(long)(row0 + r) * ldc + col] = f2bf(val);
                }
            }
        }
    }
}

// ---------------------------------------------------------------------------
// fp32 -> bf16 elementwise convert (n multiple of 2048)
// ---------------------------------------------------------------------------
__global__ __launch_bounds__(256) void f2b_kernel(
    const float* __restrict__ in, u16* __restrict__ out)
{
    const long i = ((long)blockIdx.x * 256 + threadIdx.x) * 8;
    const float4 a = *(const float4*)(in + i);
    const float4 b = *(const float4*)(in + i + 4);
    u16x8 o;
    o[0] = f2bf(a.x); o[1] = f2bf(a.y); o[2] = f2bf(a.z); o[3] = f2bf(a.w);
    o[4] = f2bf(b.x); o[5] = f2bf(b.y); o[6] = f2bf(b.z); o[7] = f2bf(b.w);
    *(u16x8*)(out + i) = o;
}

// ---------------------------------------------------------------------------
// transpose fp32 [R][C] -> bf16 [C][R]  (weights; R,C multiples of 32)
// ---------------------------------------------------------------------------
__global__ __launch_bounds__(256) void transpose_f2b_kernel(
    const float* __restrict__ in, u16* __restrict__ out, int R, int C)
{
    __shared__ float tile[32][33];
    const int tx = threadIdx.x & 31, ty = threadIdx.x >> 5;
    const int c0 = blockIdx.x * 32, r0 = blockIdx.y * 32;
    #pragma unroll
    for (int i = 0; i < 4; ++i)
        tile[ty + i * 8][tx] = in[(long)(r0 + ty + i * 8) * C + c0 + tx];
    __syncthreads();
    #pragma unroll
    for (int i = 0; i < 4; ++i)
        out[(long)(c0 + ty + i * 8) * R + r0 + tx] = f2bf(tile[tx][ty + i * 8]);
}

// ---------------------------------------------------------------------------
// transpose bf16 [R][C] (row stride lda) -> bf16 [C][R], z-batched (V^T)
// ---------------------------------------------------------------------------
__global__ __launch_bounds__(256) void transpose_b2b_kernel(
    const u16* __restrict__ in, u16* __restrict__ out, int lda, int R, int C,
    long sIz, long sOz)
{
    __shared__ u16 tile[32][33];
    in  += (long)blockIdx.z * sIz;
    out += (long)blockIdx.z * sOz;
    const int tx = threadIdx.x & 31, ty = threadIdx.x >> 5;
    const int c0 = blockIdx.x * 32, r0 = blockIdx.y * 32;
    #pragma unroll
    for (int i = 0; i < 4; ++i)
        tile[ty + i * 8][tx] = in[(long)(r0 + ty + i * 8) * lda + c0 + tx];
    __syncthreads();
    #pragma unroll
    for (int i = 0; i < 4; ++i)
        out[(long)(c0 + ty + i * 8) * R + r0 + tx] = tile[tx][ty + i * 8];
}

// ---------------------------------------------------------------------------
// Row softmax on bf16 scores in place (-> probabilities bf16). fp32 math.
// Causal mask applied by index (garbage in skipped blocks never used).
// ---------------------------------------------------------------------------
__global__ __launch_bounds__(256) void softmax_bf16_kernel(
    u16* __restrict__ S, int L, int causal, long sSz)
{
    const int i = blockIdx.x;
    u16* row = S + (long)blockIdx.y * sSz + (long)i * L;
    const int t = threadIdx.x;

    const u16x8 rv = *(const u16x8*)(row + t * 8);
    float v[8];
    float m = -INFINITY;
    #pragma unroll
    for (int e = 0; e < 8; ++e) {
        const int j = t * 8 + e;
        float val = (causal && j > i) ? -INFINITY : bf2f(rv[e]);
        v[e] = val;
        m = fmaxf(m, val);
    }
    #pragma unroll
    for (int o = 32; o > 0; o >>= 1) m = fmaxf(m, __shfl_down(m, o, 64));
    __shared__ float redm[4];
    if ((t & 63) == 0) redm[t >> 6] = m;
    __syncthreads();
    m = fmaxf(fmaxf(redm[0], redm[1]), fmaxf(redm[2], redm[3]));

    float sum = 0.f;
    #pragma unroll
    for (int e = 0; e < 8; ++e) { float ex = __expf(v[e] - m); v[e] = ex; sum += ex; }
    #pragma unroll
    for (int o = 32; o > 0; o >>= 1) sum += __shfl_down(sum, o, 64);
    __shared__ float reds[4];
    if ((t & 63) == 0) reds[t >> 6] = sum;
    __syncthreads();
    sum = reds[0] + reds[1] + reds[2] + reds[3];

    const float inv = 1.0f / sum;
    u16x8 ov;
    #pragma unroll
    for (int e = 0; e < 8; ++e) ov[e] = f2bf(v[e] * inv);
    *(u16x8*)(row + t * 8) = ov;
}

// ---------------------------------------------------------------------------
// out = LayerNorm(x + y; gamma, beta, eps=1e-3), D=1024; optional bf16 copy.
// Y is fp32 or bf16 (YT = float / u16).
// ---------------------------------------------------------------------------
template <typename YT>
__global__ __launch_bounds__(256) void add_ln_kernel(
    const float* __restrict__ X, const YT* __restrict__ Y,
    const float* __restrict__ gamma, const float* __restrict__ beta,
    float* __restrict__ out, u16* __restrict__ outb, int D)
{
    const long r = blockIdx.x;
    const int t = threadIdx.x;
    const float4 x = *(const float4*)&X[r * D + t * 4];
    float y0, y1, y2, y3;
    if (sizeof(YT) == 4) {
        const float4 y = *(const float4*)&((const float*)Y)[r * D + t * 4];
        y0 = y.x; y1 = y.y; y2 = y.z; y3 = y.w;
    } else {
        const u16x4 y = *(const u16x4*)&((const u16*)Y)[r * D + t * 4];
        y0 = bf2f(y[0]); y1 = bf2f(y[1]); y2 = bf2f(y[2]); y3 = bf2f(y[3]);
    }
    float s0 = x.x + y0, s1 = x.y + y1, s2 = x.z + y2, s3 = x.w + y3;

    float sum = s0 + s1 + s2 + s3;
    float sq  = s0 * s0 + s1 * s1 + s2 * s2 + s3 * s3;
    #pragma unroll
    for (int o = 32; o > 0; o >>= 1) {
        sum += __shfl_down(sum, o, 64);
        sq  += __shfl_down(sq, o, 64);
    }
    __shared__ float rsum[4], rsq[4];
    if ((t & 63) == 0) { rsum[t >> 6] = sum; rsq[t >> 6] = sq; }
    __syncthreads();
    sum = rsum[0] + rsum[1] + rsum[2] + rsum[3];
    sq  = rsq[0] + rsq[1] + rsq[2] + rsq[3];

    const float mu   = sum / (float)D;
    const float var  = sq / (float)D - mu * mu;
    const float rstd = rsqrtf(var + 1e-3f);

    const float4 g = *(const float4*)&gamma[t * 4];
    const float4 b = *(const float4*)&beta[t * 4];
    float4 o;
    o.x = (s0 - mu) * rstd * g.x + b.x;
    o.y = (s1 - mu) * rstd * g.y + b.y;
    o.z = (s2 - mu) * rstd * g.z + b.z;
    o.w = (s3 - mu) * rstd * g.w + b.w;
    *(float4*)&out[r * D + t * 4] = o;
    if (outb) {
        u16x4 ob;
        ob[0] = f2bf(o.x); ob[1] = f2bf(o.y); ob[2] = f2bf(o.z); ob[3] = f2bf(o.w);
        *(u16x4*)&outb[r * D + t * 4] = ob;
    }
}

// ---------------------------------------------------------------------------
extern "C" void kernel_launch(void* const* d_in, const int* in_sizes, int n_in,
                              void* d_out, int out_size, void* d_ws, size_t ws_size,
                              hipStream_t stream)
{
    const int B = BB, L = LL_, D = DD, H = HH;
    const long LD  = (long)L * D;        // 2M elems
    const long LLs = (long)L * L;        // 4M elems
    const long BLD = (long)B * LD;       // 16.78M elems
    const int  BL  = B * L;              // 16384
    const int  D3  = 3 * D;              // fused QKV width

    const float* x     = (const float*)d_in[0];
    const float* ctx   = (const float*)d_in[1];
    const float* Wk_s  = (const float*)d_in[2];
    const float* Wv_s  = (const float*)d_in[3];
    const float* Wq_s  = (const float*)d_in[4];
    const float* Wk_c  = (const float*)d_in[5];
    const float* Wv_c  = (const float*)d_in[6];
    const float* Wq_c  = (const float*)d_in[7];
    const float* W1    = (const float*)d_in[8];
    const float* b1    = (const float*)d_in[9];
    const float* W2    = (const float*)d_in[10];
    const float* b2    = (const float*)d_in[11];
    const float* gamma = (const float*)d_in[12];
    const float* beta  = (const float*)d_in[13];
    float* out = (float*)d_out;

    // ---- workspace layout (bump allocator) ----
    size_t ofs = 0;
    auto alloc = [&](size_t bytes) -> char* {
        char* p = (char*)d_ws + ofs;
        ofs += (bytes + 255) & ~(size_t)255;
        return p;
    };
    u16* WqkvTs = (u16*)alloc((size_t)3 * D * D * 2);  // [3D][D]: Q,K,V slices
    u16* WqTc   = (u16*)alloc((size_t)D * D * 2);      // [D][D]
    u16* WkvTc  = (u16*)alloc((size_t)2 * D * D * 2);  // [2D][D]: K,V slices
    u16* W1T  = (u16*)alloc((size_t)D * H * 2);        // [H][D]
    u16* W2T  = (u16*)alloc((size_t)H * D * 2);        // [D][H]
    u16* actb1 = (u16*)alloc((size_t)BLD * 2);    // xb -> ctxb -> o2b
    u16* actb2 = (u16*)alloc((size_t)BLD * 2);    // o1b
    float* o2  = (float*)alloc((size_t)BLD * 4);
    char* scratch = (char*)d_ws + ofs;
    const size_t remain = ws_size > ofs ? ws_size - ofs : 0;

    // per-batch attention scratch: qkv [L][3D] bf16 + vt [D][L] bf16
    // + P [L][L] bf16 + attn [L][D] bf16
    const size_t per_b = (size_t)(3 * LD + LD + LLs + LD) * 2;
    long gl = (long)(remain / per_b);
    const int g = gl < 1 ? 1 : (gl > B ? B : (int)gl);

    u16* qkvb = (u16*)scratch;                       // [g*L][3D]
    u16* vtb  = qkvb + (size_t)g * L * D3;           // [g][D][L]
    u16* Pb   = vtb + (size_t)g * LD;                // [g][L][L]
    u16* attnb = Pb + (size_t)g * LLs;               // [g][L][D] bf16

    const float scale = 1.0f / sqrtf((float)L);
    const dim3 blk(256);
    const dim3 blk512(512);
    const long L3D = (long)L * D3;

    // ---- weight transposes (fp32 -> bf16, [K][N] -> [N][K], into slices) ----
    transpose_f2b_kernel<<<dim3(D/32, D/32), blk, 0, stream>>>(Wq_s, WqkvTs,           D, D);
    transpose_f2b_kernel<<<dim3(D/32, D/32), blk, 0, stream>>>(Wk_s, WqkvTs + (size_t)D*D,   D, D);
    transpose_f2b_kernel<<<dim3(D/32, D/32), blk, 0, stream>>>(Wv_s, WqkvTs + (size_t)2*D*D, D, D);
    transpose_f2b_kernel<<<dim3(D/32, D/32), blk, 0, stream>>>(Wq_c, WqTc, D, D);
    transpose_f2b_kernel<<<dim3(D/32, D/32), blk, 0, stream>>>(Wk_c, WkvTc,            D, D);
    transpose_f2b_kernel<<<dim3(D/32, D/32), blk, 0, stream>>>(Wv_c, WkvTc + (size_t)D*D,   D, D);
    transpose_f2b_kernel<<<dim3(H/32, D/32), blk, 0, stream>>>(W1, W1T, D, H);
    transpose_f2b_kernel<<<dim3(D/32, H/32), blk, 0, stream>>>(W2, W2T, H, D);

    // attention tail (shared): V^T, scores, softmax, PV (bf16 out), add+LN
    auto attn_tail = [&](int gb, long off, const float* resid, float* dst,
                         u16* dstb, int causal) {
        transpose_b2b_kernel<<<dim3(D/32, L/32, gb), blk, 0, stream>>>(
            qkvb + 2 * D, vtb, D3, L, D, L3D, LD);
        if (causal) {
            gemm256_kernel<u16, false, false, true, false>
                <<<dim3(L/256, L/256, gb), blk512, 0, stream>>>(
                    qkvb, qkvb + D, nullptr, Pb, D, L, scale,
                    D3, D3, L, L3D, L3D, LLs);
        } else {
            gemm256_kernel<u16, false, false, false, false>
                <<<dim3(L/256, L/256, gb), blk512, 0, stream>>>(
                    qkvb, qkvb + D, nullptr, Pb, D, L, scale,
                    D3, D3, L, L3D, L3D, LLs);
        }
        softmax_bf16_kernel<<<dim3(L, gb), blk, 0, stream>>>(Pb, L, causal, LLs);
        if (causal) {
            gemm256_kernel<u16, false, false, false, true>
                <<<dim3(D/256, L/256, gb), blk512, 0, stream>>>(
                    Pb, vtb, nullptr, attnb, L, D, 1.f,
                    L, L, D, LLs, LD, LD);
        } else {
            gemm256_kernel<u16, false, false, false, false>
                <<<dim3(D/256, L/256, gb), blk512, 0, stream>>>(
                    Pb, vtb, nullptr, attnb, L, D, 1.f,
                    L, L, D, LLs, LD, LD);
        }
        add_ln_kernel<u16><<<dim3(gb * L), blk, 0, stream>>>(
            resid + off, attnb, gamma, beta, dst + off,
            dstb ? dstb + off : nullptr, D);
    };

    // ---- Phase A: self-attention (causal). o1 fp32 -> d_out, o1b -> actb2 ----
    f2b_kernel<<<dim3(BLD / 2048), blk, 0, stream>>>(x, actb1);       // xb
    for (int b0 = 0; b0 < B; b0 += g) {
        const int gb = (B - b0) < g ? (B - b0) : g;
        const long off = (long)b0 * LD;
        // fused QKV projection: [gb*L, D] x [D, 3D]
        gemm256_kernel<u16, false, false, false, false>
            <<<dim3(D3/256, gb*L/256), blk512, 0, stream>>>(
                actb1 + off, WqkvTs, nullptr, qkvb, D, D3, 1.f,
                D, D, D3, 0, 0, 0);
        attn_tail(gb, off, x, out, actb2, 1);
    }

    // ---- Phase B: cross-attention. o2 fp32 -> ws, o2b -> actb1 ----
    f2b_kernel<<<dim3(BLD / 2048), blk, 0, stream>>>(ctx, actb1);     // ctxb
    for (int b0 = 0; b0 < B; b0 += g) {
        const int gb = (B - b0) < g ? (B - b0) : g;
        const long off = (long)b0 * LD;
        // Q from o1b
        gemm256_kernel<u16, false, false, false, false>
            <<<dim3(D/256, gb*L/256), blk512, 0, stream>>>(
                actb2 + off, WqTc, nullptr, qkvb, D, D, 1.f,
                D, D, D3, 0, 0, 0);
        // fused KV from ctxb (o2b overwrites these rows only after consumption)
        gemm256_kernel<u16, false, false, false, false>
            <<<dim3((2*D)/256, gb*L/256), blk512, 0, stream>>>(
                actb1 + off, WkvTc, nullptr, qkvb + D, D, 2 * D, 1.f,
                D, D, D3, 0, 0, 0);
        attn_tail(gb, off, out, o2, actb1, 0);
    }

    // ---- Phase C: FFN + LN, row-chunked through scratch ----
    {
        long mc = (long)(remain / ((size_t)H * 2 + (size_t)D * 2));
        mc = (mc / 256) * 256;
        if (mc > BL) mc = BL;
        if (mc < 256) mc = 256;
        for (long m0 = 0; m0 < BL; m0 += mc) {
            const long rows = (BL - m0) < mc ? (BL - m0) : mc;
            u16* h = (u16*)scratch;                          // [rows, H] bf16
            u16* ff = (u16*)(scratch + (size_t)rows * H * 2);  // [rows, D] bf16
            gemm256_kernel<u16, true, true, false, false>
                <<<dim3(H/256, rows/256), blk512, 0, stream>>>(
                    actb1 + m0 * D, W1T, b1, h, D, H, 1.f,
                    D, D, H, 0, 0, 0);
            gemm256_kernel<u16, true, false, false, false>
                <<<dim3(D/256, rows/256), blk512, 0, stream>>>(
                    h, W2T, b2, ff, H, D, 1.f,
                    H, H, D, 0, 0, 0);
            add_ln_kernel<u16><<<dim3(rows), blk, 0, stream>>>(
                o2 + m0 * D, ff, gamma, beta, out + m0 * D, nullptr, D);
        }
    }
}

// Round 10
// 1013.779 us; speedup vs baseline: 1.6137x; 1.2123x over previous
//
#include <hip/hip_runtime.h>
#include <math.h>

// Problem dims (fixed by reference setup_inputs)
#define BB 8
#define LL_ 2048
#define DD 1024
#define HH 2048

typedef unsigned short u16;
typedef __attribute__((ext_vector_type(8))) u16 u16x8;
typedef __attribute__((ext_vector_type(4))) u16 u16x4;
typedef __attribute__((ext_vector_type(8))) __bf16 bf16x8;
typedef __attribute__((ext_vector_type(4))) float f32x4;

__device__ __forceinline__ u16 f2bf(float f) {
    union { float f; unsigned u; } v; v.f = f;
    unsigned r = (v.u + 0x7FFFu + ((v.u >> 16) & 1u)) >> 16;
    return (u16)r;
}
__device__ __forceinline__ float bf2f(u16 h) {
    union { unsigned u; float f; } v; v.u = ((unsigned)h) << 16;
    return v.f;
}

// async global->LDS, 16 bytes per lane (global_load_lds_dwordx4)
__device__ __forceinline__ void gload16(const u16* g, u16* l) {
    __builtin_amdgcn_global_load_lds(
        (const __attribute__((address_space(1))) unsigned*)g,
        (__attribute__((address_space(3))) unsigned*)l, 16, 0, 0);
}

// MFMA quadrant: 4m x 2n frags x 2 ksub = 16 MFMA, constexpr acc indices.
template <int MH, int NH>
__device__ __forceinline__ void quad(f32x4 (&acc)[8][4],
                                     const bf16x8 (&aF)[4][2],
                                     const bf16x8 (&bF)[2][2]) {
    #pragma unroll
    for (int mq = 0; mq < 4; ++mq)
        #pragma unroll
        for (int nq = 0; nq < 2; ++nq)
            #pragma unroll
            for (int ks = 0; ks < 2; ++ks)
                acc[MH * 4 + mq][NH * 2 + nq] =
                    __builtin_amdgcn_mfma_f32_16x16x32_bf16(
                        aF[mq][ks], bF[nq][ks], acc[MH * 4 + mq][NH * 2 + nq],
                        0, 0, 0);
}

// ---------------------------------------------------------------------------
// 256x256 8-phase bf16 MFMA GEMM, NT form: C[M,N] = A[M,K] @ Bt[N,K]^T with
// row strides lda/ldb/ldc.  512 threads = 8 waves (2x4); wave tile 128x64 =
// 8x4 frags of 16x16x32.  BK=64 K-tiles, double-buffered 128 KiB LDS,
// half-tile staging via global_load_lds with inverse-swizzled source;
// ds_read swizzle byte ^= ((row&7)<<4) -> conflict-free.  Counted vmcnt(4)
// at phases 4/8 only.  STG never skips (source clamped to nt-1, dead dest
// slot) so the vmcnt ledger is uniform.  Chunked XCD swizzle (bijective when
// nwg%8==0) for L2 panel locality.  bf16 outputs go through an LDS-staged
// coalesced epilogue (512B-per-row u16x8 stores) using the dead staging LDS.
// CSKIP: skip blocks fully above causal diagonal.  CKEND: kend=i0+256 (P@V).
// ---------------------------------------------------------------------------
template <typename OutT, bool BIAS, bool RELU, bool CSKIP, bool CKEND>
__global__ __launch_bounds__(512, 2) void gemm256_kernel(
    const u16* __restrict__ A, const u16* __restrict__ Bt,
    const float* __restrict__ bias, OutT* __restrict__ C,
    int K, int N, float scale, int lda, int ldb, int ldc,
    long sAz, long sBz, long sCz)
{
    // chunked XCD swizzle: same-XCD blocks get contiguous linear ids
    int bx = blockIdx.x, by = blockIdx.y;
    {
        const int nwg = gridDim.x * gridDim.y;
        if ((nwg & 7) == 0) {
            int bid = by * gridDim.x + bx;
            bid = (bid & 7) * (nwg >> 3) + (bid >> 3);
            bx = bid % gridDim.x;
            by = bid / gridDim.x;
        }
    }
    const int i0 = by * 256;   // M block
    const int n0 = bx * 256;   // N block
    if (CSKIP && n0 > i0 + 255) return;

    A  += (long)blockIdx.z * sAz;
    Bt += (long)blockIdx.z * sBz;
    C  += (long)blockIdx.z * sCz;

    // 2 bufs x (A: 2 halves + B: 2 halves) x 16 KiB = 128 KiB
    __shared__ u16 lds[65536];

    int kend = K;
    if (CKEND) { int ke = i0 + 256; kend = ke < K ? ke : K; }
    const int nt = kend >> 6;          // K-tiles of 64 (even, >=4 here)

    const int t   = threadIdx.x;
    const int wid = t >> 6, l = t & 63;
    const int wr  = wid >> 2, wc = wid & 3;   // 2x4 wave grid
    const int lg  = l >> 4,  lr = l & 15;

    // staging: thread t -> half-tile row srow(+64), logical k-chunk sch
    // (inverse swizzle so linear LDS dest yields swizzled layout)
    const int srow = t >> 3;                    // 0..63
    const int sch  = (t & 7) ^ (srow & 7);      // logical 8-elem chunk

    // swizzled read slots (u16 units): chunk c at byte (c ^ (row&7))*16
    const int slot0 = ((lg) ^ (lr & 7)) * 8;        // ksub=0, chunk=lg
    const int slot1 = ((4 + lg) ^ (lr & 7)) * 8;    // ksub=1, chunk=4+lg

    f32x4 acc[8][4];
    #pragma unroll
    for (int m = 0; m < 8; ++m)
        #pragma unroll
        for (int n = 0; n < 4; ++n)
            acc[m][n] = (f32x4){0.f, 0.f, 0.f, 0.f};

    bf16x8 aF[4][2], bF0[2][2], bF1[2][2];

    auto readA_f = [&](int bufb, int mh) {
        const u16* base = lds + bufb + wr * 8192 + mh * 4096 + lr * 64;
        #pragma unroll
        for (int mq = 0; mq < 4; ++mq) {
            aF[mq][0] = *(const bf16x8*)(base + mq * 1024 + slot0);
            aF[mq][1] = *(const bf16x8*)(base + mq * 1024 + slot1);
        }
    };
    auto readB_f = [&](int bufb, int nh, bf16x8 (&bf)[2][2]) {
        const u16* base = lds + bufb + 16384 + (wc >> 1) * 8192 +
                          (wc & 1) * 4096 + nh * 2048 + lr * 64;
        #pragma unroll
        for (int nq = 0; nq < 2; ++nq) {
            bf[nq][0] = *(const bf16x8*)(base + nq * 1024 + slot0);
            bf[nq][1] = *(const bf16x8*)(base + nq * 1024 + slot1);
        }
    };
    // which: 0=A-half0, 1=A-half1, 2=B-half0, 3=B-half1.
    // Source tile clamped to nt-1 (dest slot from ORIGINAL tile parity is
    // dead when tile >= nt) so the vmcnt ledger stays uniform.
    auto STG = [&](int tile, int which) {
        const int  st  = tile < nt ? tile : nt - 1;
        const bool isB = which >= 2;
        const int  h   = which & 1;
        const u16* src = isB ? Bt : A;
        const int  ld  = isB ? ldb : lda;
        const int  r0  = (isB ? n0 : i0) + h * 128 + srow;
        const long g   = (long)r0 * ld + st * 64 + sch * 8;
        u16* d = lds + (tile & 1) * 32768 + (isB ? 16384 : 0) + h * 8192 + t * 8;
        gload16(src + g, d);
        gload16(src + g + (long)64 * ld, d + 4096);
    };

#define PHASE(MH, NH, RA, RB, BF, BUFB, STILE, SWHICH, VM4)                 \
    {                                                                       \
        if (RA) readA_f(BUFB, MH);                                          \
        if (RB) readB_f(BUFB, NH, BF);                                      \
        STG(STILE, SWHICH);                                                 \
        if (VM4) asm volatile("s_waitcnt vmcnt(4)" ::: "memory");           \
        asm volatile("s_barrier" ::: "memory");                             \
        __builtin_amdgcn_s_setprio(1);                                      \
        quad<MH, NH>(acc, aF, BF);                                          \
        __builtin_amdgcn_s_setprio(0);                                      \
        asm volatile("s_barrier" ::: "memory");                             \
    }

    // prologue: T0 {B0,B1,A0,A1}, T1 {B0,B1}; wait all but newest 2 halves
    STG(0, 2); STG(0, 3); STG(0, 0); STG(0, 1);
    STG(1, 2); STG(1, 3);
    asm volatile("s_waitcnt vmcnt(4)" ::: "memory");
    asm volatile("s_barrier" ::: "memory");

    for (int j = 0; j < nt; j += 2) {
        // K-tile j in buf0 (phases 1-4), j+1 in buf1 (phases 5-8)
        PHASE(0, 0, 1, 1, bF0, 0,     j + 1, 0, 0)   // stage A0(j+1)
        PHASE(0, 1, 0, 1, bF1, 0,     j + 1, 1, 0)   // stage A1(j+1)
        PHASE(1, 1, 1, 0, bF1, 0,     j + 2, 2, 0)   // stage B0(j+2)
        PHASE(1, 0, 0, 0, bF0, 0,     j + 2, 3, 1)   // stage B1(j+2), vmcnt(4)
        PHASE(0, 0, 1, 1, bF0, 32768, j + 2, 0, 0)   // stage A0(j+2)
        PHASE(0, 1, 0, 1, bF1, 32768, j + 2, 1, 0)   // stage A1(j+2)
        PHASE(1, 1, 1, 0, bF1, 32768, j + 3, 2, 0)   // stage B0(j+3)
        PHASE(1, 0, 0, 0, bF0, 32768, j + 3, 3, 1)   // stage B1(j+3), vmcnt(4)
    }
#undef PHASE

    // drain in-flight LDS-DMA (dead-slot stages); then LDS is dead storage
    asm volatile("s_waitcnt vmcnt(0)" ::: "memory");

    if (sizeof(OutT) == 4) {
        // fp32 path: direct stores (col = lane&15, row = (lane>>4)*4 + r)
        #pragma unroll
        for (int nj = 0; nj < 4; ++nj) {
            const int col = n0 + wc * 64 + nj * 16 + lr;
            const float bv = BIAS ? bias[col] : 0.f;
            #pragma unroll
            for (int mi = 0; mi < 8; ++mi) {
                const int row0 = i0 + wr * 128 + mi * 16 + lg * 4;
                #pragma unroll
                for (int r = 0; r < 4; ++r) {
                    float val = acc[mi][nj][r] * scale + bv;
                    if (RELU) val = fmaxf(val, 0.f);
                    ((float*)C)[(long)(row0 + r) * ldc + col] = val;
                }
            }
        }
    } else {
        // bf16 path: stage C tile (256x256 u16) in LDS with chunk-XOR
        // swizzle (bank-spread across the 4 lg rows), then coalesced
        // 512B-per-row u16x8 stores.
        __syncthreads();   // ALL waves' DMAs drained before LDS reuse
        #pragma unroll
        for (int nj = 0; nj < 4; ++nj) {
            const int cl = wc * 64 + nj * 16 + lr;      // tile-local col
            const float bv = BIAS ? bias[n0 + cl] : 0.f;
            #pragma unroll
            for (int mi = 0; mi < 8; ++mi) {
                const int rb = wr * 128 + mi * 16 + lg * 4;  // tile-local row
                const int sw = ((cl >> 3) ^ ((rb >> 2) & 7)) << 3;
                #pragma unroll
                for (int r = 0; r < 4; ++r) {
                    float val = acc[mi][nj][r] * scale + bv;
                    if (RELU) val = fmaxf(val, 0.f);
                    lds[(rb + r) * 256 + sw + (cl & 7)] = f2bf(val);
                }
            }
        }
        __syncthreads();
        #pragma unroll
        for (int i = 0; i < 16; ++i) {
            const int idx = i * 512 + t;
            const int row = idx >> 5;       // 32 chunks of 16B per row
            const int ch  = idx & 31;
            const int sw  = ch ^ ((row >> 2) & 7);
            const u16x8 v = *(const u16x8*)(lds + row * 256 + sw * 8);
            *(u16x8*)&((u16*)C)[(long)(i0 + row) * ldc + n0 + ch * 8] = v;
        }
    }
}

// ---------------------------------------------------------------------------
// fp32 -> bf16 elementwise convert (n multiple of 2048)
// ---------------------------------------------------------------------------
__global__ __launch_bounds__(256) void f2b_kernel(
    const float* __restrict__ in, u16* __restrict__ out)
{
    const long i = ((long)blockIdx.x * 256 + threadIdx.x) * 8;
    const float4 a = *(const float4*)(in + i);
    const float4 b = *(const float4*)(in + i + 4);
    u16x8 o;
    o[0] = f2bf(a.x); o[1] = f2bf(a.y); o[2] = f2bf(a.z); o[3] = f2bf(a.w);
    o[4] = f2bf(b.x); o[5] = f2bf(b.y); o[6] = f2bf(b.z); o[7] = f2bf(b.w);
    *(u16x8*)(out + i) = o;
}

// ---------------------------------------------------------------------------
// transpose fp32 [R][C] -> bf16 [C][R]  (weights; R,C multiples of 32)
// ---------------------------------------------------------------------------
__global__ __launch_bounds__(256) void transpose_f2b_kernel(
    const float* __restrict__ in, u16* __restrict__ out, int R, int C)
{
    __shared__ float tile[32][33];
    const int tx = threadIdx.x & 31, ty = threadIdx.x >> 5;
    const int c0 = blockIdx.x * 32, r0 = blockIdx.y * 32;
    #pragma unroll
    for (int i = 0; i < 4; ++i)
        tile[ty + i * 8][tx] = in[(long)(r0 + ty + i * 8) * C + c0 + tx];
    __syncthreads();
    #pragma unroll
    for (int i = 0; i < 4; ++i)
        out[(long)(c0 + ty + i * 8) * R + r0 + tx] = f2bf(tile[tx][ty + i * 8]);
}

// ---------------------------------------------------------------------------
// Row softmax on bf16 scores in place (-> probabilities bf16). fp32 math.
// Causal mask applied by index (garbage in skipped blocks never used).
// ---------------------------------------------------------------------------
__global__ __launch_bounds__(256) void softmax_bf16_kernel(
    u16* __restrict__ S, int L, int causal, long sSz)
{
    const int i = blockIdx.x;
    u16* row = S + (long)blockIdx.y * sSz + (long)i * L;
    const int t = threadIdx.x;

    const u16x8 rv = *(const u16x8*)(row + t * 8);
    float v[8];
    float m = -INFINITY;
    #pragma unroll
    for (int e = 0; e < 8; ++e) {
        const int j = t * 8 + e;
        float val = (causal && j > i) ? -INFINITY : bf2f(rv[e]);
        v[e] = val;
        m = fmaxf(m, val);
    }
    #pragma unroll
    for (int o = 32; o > 0; o >>= 1) m = fmaxf(m, __shfl_down(m, o, 64));
    __shared__ float redm[4];
    if ((t & 63) == 0) redm[t >> 6] = m;
    __syncthreads();
    m = fmaxf(fmaxf(redm[0], redm[1]), fmaxf(redm[2], redm[3]));

    float sum = 0.f;
    #pragma unroll
    for (int e = 0; e < 8; ++e) { float ex = __expf(v[e] - m); v[e] = ex; sum += ex; }
    #pragma unroll
    for (int o = 32; o > 0; o >>= 1) sum += __shfl_down(sum, o, 64);
    __shared__ float reds[4];
    if ((t & 63) == 0) reds[t >> 6] = sum;
    __syncthreads();
    sum = reds[0] + reds[1] + reds[2] + reds[3];

    const float inv = 1.0f / sum;
    u16x8 ov;
    #pragma unroll
    for (int e = 0; e < 8; ++e) ov[e] = f2bf(v[e] * inv);
    *(u16x8*)(row + t * 8) = ov;
}

// ---------------------------------------------------------------------------
// out = LayerNorm(x + y; gamma, beta, eps=1e-3), D=1024; optional bf16 copy.
// Y is fp32 or bf16 (YT = float / u16).
// ---------------------------------------------------------------------------
template <typename YT>
__global__ __launch_bounds__(256) void add_ln_kernel(
    const float* __restrict__ X, const YT* __restrict__ Y,
    const float* __restrict__ gamma, const float* __restrict__ beta,
    float* __restrict__ out, u16* __restrict__ outb, int D)
{
    const long r = blockIdx.x;
    const int t = threadIdx.x;
    const float4 x = *(const float4*)&X[r * D + t * 4];
    float y0, y1, y2, y3;
    if (sizeof(YT) == 4) {
        const float4 y = *(const float4*)&((const float*)Y)[r * D + t * 4];
        y0 = y.x; y1 = y.y; y2 = y.z; y3 = y.w;
    } else {
        const u16x4 y = *(const u16x4*)&((const u16*)Y)[r * D + t * 4];
        y0 = bf2f(y[0]); y1 = bf2f(y[1]); y2 = bf2f(y[2]); y3 = bf2f(y[3]);
    }
    float s0 = x.x + y0, s1 = x.y + y1, s2 = x.z + y2, s3 = x.w + y3;

    float sum = s0 + s1 + s2 + s3;
    float sq  = s0 * s0 + s1 * s1 + s2 * s2 + s3 * s3;
    #pragma unroll
    for (int o = 32; o > 0; o >>= 1) {
        sum += __shfl_down(sum, o, 64);
        sq  += __shfl_down(sq, o, 64);
    }
    __shared__ float rsum[4], rsq[4];
    if ((t & 63) == 0) { rsum[t >> 6] = sum; rsq[t >> 6] = sq; }
    __syncthreads();
    sum = rsum[0] + rsum[1] + rsum[2] + rsum[3];
    sq  = rsq[0] + rsq[1] + rsq[2] + rsq[3];

    const float mu   = sum / (float)D;
    const float var  = sq / (float)D - mu * mu;
    const float rstd = rsqrtf(var + 1e-3f);

    const float4 g = *(const float4*)&gamma[t * 4];
    const float4 b = *(const float4*)&beta[t * 4];
    float4 o;
    o.x = (s0 - mu) * rstd * g.x + b.x;
    o.y = (s1 - mu) * rstd * g.y + b.y;
    o.z = (s2 - mu) * rstd * g.z + b.z;
    o.w = (s3 - mu) * rstd * g.w + b.w;
    *(float4*)&out[r * D + t * 4] = o;
    if (outb) {
        u16x4 ob;
        ob[0] = f2bf(o.x); ob[1] = f2bf(o.y); ob[2] = f2bf(o.z); ob[3] = f2bf(o.w);
        *(u16x4*)&outb[r * D + t * 4] = ob;
    }
}

// ---------------------------------------------------------------------------
extern "C" void kernel_launch(void* const* d_in, const int* in_sizes, int n_in,
                              void* d_out, int out_size, void* d_ws, size_t ws_size,
                              hipStream_t stream)
{
    const int B = BB, L = LL_, D = DD, H = HH;
    const long LD  = (long)L * D;        // 2M elems
    const long LLs = (long)L * L;        // 4M elems
    const long BLD = (long)B * LD;       // 16.78M elems
    const int  BL  = B * L;              // 16384
    const int  D2  = 2 * D;              // fused QK width

    const float* x     = (const float*)d_in[0];
    const float* ctx   = (const float*)d_in[1];
    const float* Wk_s  = (const float*)d_in[2];
    const float* Wv_s  = (const float*)d_in[3];
    const float* Wq_s  = (const float*)d_in[4];
    const float* Wk_c  = (const float*)d_in[5];
    const float* Wv_c  = (const float*)d_in[6];
    const float* Wq_c  = (const float*)d_in[7];
    const float* W1    = (const float*)d_in[8];
    const float* b1    = (const float*)d_in[9];
    const float* W2    = (const float*)d_in[10];
    const float* b2    = (const float*)d_in[11];
    const float* gamma = (const float*)d_in[12];
    const float* beta  = (const float*)d_in[13];
    float* out = (float*)d_out;

    // ---- workspace layout (bump allocator) ----
    size_t ofs = 0;
    auto alloc = [&](size_t bytes) -> char* {
        char* p = (char*)d_ws + ofs;
        ofs += (bytes + 255) & ~(size_t)255;
        return p;
    };
    u16* WqkTs = (u16*)alloc((size_t)2 * D * D * 2);  // [2D][D]: Q,K slices
    u16* WvTs  = (u16*)alloc((size_t)D * D * 2);      // [D][D]
    u16* WqTc  = (u16*)alloc((size_t)D * D * 2);
    u16* WkTc  = (u16*)alloc((size_t)D * D * 2);
    u16* WvTc  = (u16*)alloc((size_t)D * D * 2);
    u16* W1T  = (u16*)alloc((size_t)D * H * 2);       // [H][D]
    u16* W2T  = (u16*)alloc((size_t)H * D * 2);       // [D][H]
    u16* actb1 = (u16*)alloc((size_t)BLD * 2);    // xb -> ctxb -> o2b
    u16* actb2 = (u16*)alloc((size_t)BLD * 2);    // o1b
    float* o2  = (float*)alloc((size_t)BLD * 4);
    char* scratch = (char*)d_ws + ofs;
    const size_t remain = ws_size > ofs ? ws_size - ofs : 0;

    // per-batch attention scratch: qk [L][2D] + vt [D][L] + P [L][L]
    // + attn [L][D], all bf16
    const size_t per_b = (size_t)(2 * LD + LD + LLs + LD) * 2;
    long gl = (long)(remain / per_b);
    const int g = gl < 1 ? 1 : (gl > B ? B : (int)gl);

    u16* qkb  = (u16*)scratch;                       // [g*L][2D]
    u16* vtb  = qkb + (size_t)g * L * D2;            // [g][D][L]
    u16* Pb   = vtb + (size_t)g * LD;                // [g][L][L]
    u16* attnb = Pb + (size_t)g * LLs;               // [g][L][D] bf16

    const float scale = 1.0f / sqrtf((float)L);
    const dim3 blk(256);
    const dim3 blk512(512);
    const long L2D = (long)L * D2;

    // ---- weight transposes (fp32 -> bf16, [K][N] -> [N][K], into slices) ----
    transpose_f2b_kernel<<<dim3(D/32, D/32), blk, 0, stream>>>(Wq_s, WqkTs,           D, D);
    transpose_f2b_kernel<<<dim3(D/32, D/32), blk, 0, stream>>>(Wk_s, WqkTs + (size_t)D*D, D, D);
    transpose_f2b_kernel<<<dim3(D/32, D/32), blk, 0, stream>>>(Wv_s, WvTs, D, D);
    transpose_f2b_kernel<<<dim3(D/32, D/32), blk, 0, stream>>>(Wq_c, WqTc, D, D);
    transpose_f2b_kernel<<<dim3(D/32, D/32), blk, 0, stream>>>(Wk_c, WkTc, D, D);
    transpose_f2b_kernel<<<dim3(D/32, D/32), blk, 0, stream>>>(Wv_c, WvTc, D, D);
    transpose_f2b_kernel<<<dim3(H/32, D/32), blk, 0, stream>>>(W1, W1T, D, H);
    transpose_f2b_kernel<<<dim3(D/32, H/32), blk, 0, stream>>>(W2, W2T, H, D);

    // V^T via swapped-operand GEMM: vt[d][l] = sum_k Wv[k][d] * src[l][k]
    auto vt_gemm = [&](const u16* WvT, const u16* srcb, long off, int gb) {
        gemm256_kernel<u16, false, false, false, false>
            <<<dim3(L/256, D/256, gb), blk512, 0, stream>>>(
                WvT, srcb + off, nullptr, vtb, D, L, 1.f,
                D, D, L, 0, LD, LD);
    };

    // attention tail (shared): scores, softmax, PV, add+LN
    auto attn_tail = [&](int gb, long off, const float* resid, float* dst,
                         u16* dstb, int causal) {
        if (causal) {
            gemm256_kernel<u16, false, false, true, false>
                <<<dim3(L/256, L/256, gb), blk512, 0, stream>>>(
                    qkb, qkb + D, nullptr, Pb, D, L, scale,
                    D2, D2, L, L2D, L2D, LLs);
        } else {
            gemm256_kernel<u16, false, false, false, false>
                <<<dim3(L/256, L/256, gb), blk512, 0, stream>>>(
                    qkb, qkb + D, nullptr, Pb, D, L, scale,
                    D2, D2, L, L2D, L2D, LLs);
        }
        softmax_bf16_kernel<<<dim3(L, gb), blk, 0, stream>>>(Pb, L, causal, LLs);
        if (causal) {
            gemm256_kernel<u16, false, false, false, true>
                <<<dim3(D/256, L/256, gb), blk512, 0, stream>>>(
                    Pb, vtb, nullptr, attnb, L, D, 1.f,
                    L, L, D, LLs, LD, LD);
        } else {
            gemm256_kernel<u16, false, false, false, false>
                <<<dim3(D/256, L/256, gb), blk512, 0, stream>>>(
                    Pb, vtb, nullptr, attnb, L, D, 1.f,
                    L, L, D, LLs, LD, LD);
        }
        add_ln_kernel<u16><<<dim3(gb * L), blk, 0, stream>>>(
            resid + off, attnb, gamma, beta, dst + off,
            dstb ? dstb + off : nullptr, D);
    };

    // ---- Phase A: self-attention (causal). o1 fp32 -> d_out, o1b -> actb2 ----
    f2b_kernel<<<dim3(BLD / 2048), blk, 0, stream>>>(x, actb1);       // xb
    for (int b0 = 0; b0 < B; b0 += g) {
        const int gb = (B - b0) < g ? (B - b0) : g;
        const long off = (long)b0 * LD;
        // fused QK projection: [gb*L, D] x [D, 2D]
        gemm256_kernel<u16, false, false, false, false>
            <<<dim3(D2/256, gb*L/256), blk512, 0, stream>>>(
                actb1 + off, WqkTs, nullptr, qkb, D, D2, 1.f,
                D, D, D2, 0, 0, 0);
        vt_gemm(WvTs, actb1, off, gb);
        attn_tail(gb, off, x, out, actb2, 1);
    }

    // ---- Phase B: cross-attention. o2 fp32 -> ws, o2b -> actb1 ----
    f2b_kernel<<<dim3(BLD / 2048), blk, 0, stream>>>(ctx, actb1);     // ctxb
    for (int b0 = 0; b0 < B; b0 += g) {
        const int gb = (B - b0) < g ? (B - b0) : g;
        const long off = (long)b0 * LD;
        // Q from o1b
        gemm256_kernel<u16, false, false, false, false>
            <<<dim3(D/256, gb*L/256), blk512, 0, stream>>>(
                actb2 + off, WqTc, nullptr, qkb, D, D, 1.f,
                D, D, D2, 0, 0, 0);
        // K from ctxb (o2b overwrites these rows only after consumption)
        gemm256_kernel<u16, false, false, false, false>
            <<<dim3(D/256, gb*L/256), blk512, 0, stream>>>(
                actb1 + off, WkTc, nullptr, qkb + D, D, D, 1.f,
                D, D, D2, 0, 0, 0);
        vt_gemm(WvTc, actb1, off, gb);
        attn_tail(gb, off, out, o2, actb1, 0);
    }

    // ---- Phase C: FFN + LN, row-chunked through scratch ----
    {
        long mc = (long)(remain / ((size_t)H * 2 + (size_t)D * 2));
        mc = (mc / 256) * 256;
        if (mc > BL) mc = BL;
        if (mc < 256) mc = 256;
        for (long m0 = 0; m0 < BL; m0 += mc) {
            const long rows = (BL - m0) < mc ? (BL - m0) : mc;
            u16* h = (u16*)scratch;                          // [rows, H] bf16
            u16* ff = (u16*)(scratch + (size_t)rows * H * 2);  // [rows, D] bf16
            gemm256_kernel<u16, true, true, false, false>
                <<<dim3(H/256, rows/256), blk512, 0, stream>>>(
                    actb1 + m0 * D, W1T, b1, h, D, H, 1.f,
                    D, D, H, 0, 0, 0);
            gemm256_kernel<u16, true, false, false, false>
                <<<dim3(D/256, rows/256), blk512, 0, stream>>>(
                    h, W2T, b2, ff, H, D, 1.f,
                    H, H, D, 0, 0, 0);
            add_ln_kernel<u16><<<dim3(rows), blk, 0, stream>>>(
                o2 + m0 * D, ff, gamma, beta, out + m0 * D, nullptr, D);
        }
    }
}

// Round 11
// 948.768 us; speedup vs baseline: 1.7242x; 1.0685x over previous
//
#include <hip/hip_runtime.h>
#include <math.h>

// Problem dims (fixed by reference setup_inputs)
#define BB 8
#define LL_ 2048
#define DD 1024
#define HH 2048

typedef unsigned short u16;
typedef __attribute__((ext_vector_type(8))) u16 u16x8;
typedef __attribute__((ext_vector_type(4))) u16 u16x4;
typedef __attribute__((ext_vector_type(8))) __bf16 bf16x8;
typedef __attribute__((ext_vector_type(4))) float f32x4;

__device__ __forceinline__ u16 f2bf(float f) {
    union { float f; unsigned u; } v; v.f = f;
    unsigned r = (v.u + 0x7FFFu + ((v.u >> 16) & 1u)) >> 16;
    return (u16)r;
}
__device__ __forceinline__ float bf2f(u16 h) {
    union { unsigned u; float f; } v; v.u = ((unsigned)h) << 16;
    return v.f;
}

// async global->LDS, 16 bytes per lane (global_load_lds_dwordx4)
__device__ __forceinline__ void gload16(const u16* g, u16* l) {
    __builtin_amdgcn_global_load_lds(
        (const __attribute__((address_space(1))) unsigned*)g,
        (__attribute__((address_space(3))) unsigned*)l, 16, 0, 0);
}

// MFMA quadrant: 4m x 2n frags x 2 ksub = 16 MFMA, constexpr acc indices.
template <int MH, int NH>
__device__ __forceinline__ void quad(f32x4 (&acc)[8][4],
                                     const bf16x8 (&aF)[4][2],
                                     const bf16x8 (&bF)[2][2]) {
    #pragma unroll
    for (int mq = 0; mq < 4; ++mq)
        #pragma unroll
        for (int nq = 0; nq < 2; ++nq)
            #pragma unroll
            for (int ks = 0; ks < 2; ++ks)
                acc[MH * 4 + mq][NH * 2 + nq] =
                    __builtin_amdgcn_mfma_f32_16x16x32_bf16(
                        aF[mq][ks], bF[nq][ks], acc[MH * 4 + mq][NH * 2 + nq],
                        0, 0, 0);
}

// ---------------------------------------------------------------------------
// 256x256 8-phase bf16 MFMA GEMM, NT form: C[M,N] = A[M,K] @ Bt[N,K]^T with
// row strides lda/ldb/ldc.  512 threads = 8 waves (2x4); wave tile 128x64 =
// 8x4 frags of 16x16x32.  BK=64 K-tiles, double-buffered 128 KiB LDS,
// half-tile staging via global_load_lds with inverse-swizzled source;
// ds_read swizzle byte ^= ((row&7)<<4) -> conflict-free.  Counted vmcnt(4)
// at phases 4/8 only.  STG never skips (source clamped to nt-1, dead dest
// slot) so the vmcnt ledger is uniform.  Chunked XCD swizzle (bijective when
// nwg%8==0) for L2 panel locality.  bf16 outputs go through an LDS-staged
// coalesced epilogue (512B-per-row u16x8 stores) using the dead staging LDS.
// CSKIP: skip blocks fully above causal diagonal.  CKEND: kend=i0+256 (P@V).
// ---------------------------------------------------------------------------
template <typename OutT, bool BIAS, bool RELU, bool CSKIP, bool CKEND>
__global__ __launch_bounds__(512, 2) void gemm256_kernel(
    const u16* __restrict__ A, const u16* __restrict__ Bt,
    const float* __restrict__ bias, OutT* __restrict__ C,
    int K, int N, float scale, int lda, int ldb, int ldc,
    long sAz, long sBz, long sCz)
{
    // chunked XCD swizzle: same-XCD blocks get contiguous linear ids
    int bx = blockIdx.x, by = blockIdx.y;
    {
        const int nwg = gridDim.x * gridDim.y;
        if ((nwg & 7) == 0) {
            int bid = by * gridDim.x + bx;
            bid = (bid & 7) * (nwg >> 3) + (bid >> 3);
            bx = bid % gridDim.x;
            by = bid / gridDim.x;
        }
    }
    const int i0 = by * 256;   // M block
    const int n0 = bx * 256;   // N block
    if (CSKIP && n0 > i0 + 255) return;

    A  += (long)blockIdx.z * sAz;
    Bt += (long)blockIdx.z * sBz;
    C  += (long)blockIdx.z * sCz;

    // 2 bufs x (A: 2 halves + B: 2 halves) x 16 KiB = 128 KiB
    __shared__ u16 lds[65536];

    int kend = K;
    if (CKEND) { int ke = i0 + 256; kend = ke < K ? ke : K; }
    const int nt = kend >> 6;          // K-tiles of 64 (even, >=4 here)

    const int t   = threadIdx.x;
    const int wid = t >> 6, l = t & 63;
    const int wr  = wid >> 2, wc = wid & 3;   // 2x4 wave grid
    const int lg  = l >> 4,  lr = l & 15;

    // staging: thread t -> half-tile row srow(+64), logical k-chunk sch
    // (inverse swizzle so linear LDS dest yields swizzled layout)
    const int srow = t >> 3;                    // 0..63
    const int sch  = (t & 7) ^ (srow & 7);      // logical 8-elem chunk

    // swizzled read slots (u16 units): chunk c at byte (c ^ (row&7))*16
    const int slot0 = ((lg) ^ (lr & 7)) * 8;        // ksub=0, chunk=lg
    const int slot1 = ((4 + lg) ^ (lr & 7)) * 8;    // ksub=1, chunk=4+lg

    f32x4 acc[8][4];
    #pragma unroll
    for (int m = 0; m < 8; ++m)
        #pragma unroll
        for (int n = 0; n < 4; ++n)
            acc[m][n] = (f32x4){0.f, 0.f, 0.f, 0.f};

    bf16x8 aF[4][2], bF0[2][2], bF1[2][2];

    auto readA_f = [&](int bufb, int mh) {
        const u16* base = lds + bufb + wr * 8192 + mh * 4096 + lr * 64;
        #pragma unroll
        for (int mq = 0; mq < 4; ++mq) {
            aF[mq][0] = *(const bf16x8*)(base + mq * 1024 + slot0);
            aF[mq][1] = *(const bf16x8*)(base + mq * 1024 + slot1);
        }
    };
    auto readB_f = [&](int bufb, int nh, bf16x8 (&bf)[2][2]) {
        const u16* base = lds + bufb + 16384 + (wc >> 1) * 8192 +
                          (wc & 1) * 4096 + nh * 2048 + lr * 64;
        #pragma unroll
        for (int nq = 0; nq < 2; ++nq) {
            bf[nq][0] = *(const bf16x8*)(base + nq * 1024 + slot0);
            bf[nq][1] = *(const bf16x8*)(base + nq * 1024 + slot1);
        }
    };
    // which: 0=A-half0, 1=A-half1, 2=B-half0, 3=B-half1.
    // Source tile clamped to nt-1 (dest slot from ORIGINAL tile parity is
    // dead when tile >= nt) so the vmcnt ledger stays uniform.
    auto STG = [&](int tile, int which) {
        const int  st  = tile < nt ? tile : nt - 1;
        const bool isB = which >= 2;
        const int  h   = which & 1;
        const u16* src = isB ? Bt : A;
        const int  ld  = isB ? ldb : lda;
        const int  r0  = (isB ? n0 : i0) + h * 128 + srow;
        const long g   = (long)r0 * ld + st * 64 + sch * 8;
        u16* d = lds + (tile & 1) * 32768 + (isB ? 16384 : 0) + h * 8192 + t * 8;
        gload16(src + g, d);
        gload16(src + g + (long)64 * ld, d + 4096);
    };

#define PHASE(MH, NH, RA, RB, BF, BUFB, STILE, SWHICH, VM4)                 \
    {                                                                       \
        if (RA) readA_f(BUFB, MH);                                          \
        if (RB) readB_f(BUFB, NH, BF);                                      \
        STG(STILE, SWHICH);                                                 \
        if (VM4) asm volatile("s_waitcnt vmcnt(4)" ::: "memory");           \
        asm volatile("s_barrier" ::: "memory");                             \
        __builtin_amdgcn_s_setprio(1);                                      \
        quad<MH, NH>(acc, aF, BF);                                          \
        __builtin_amdgcn_s_setprio(0);                                      \
        asm volatile("s_barrier" ::: "memory");                             \
    }

    // prologue: T0 {B0,B1,A0,A1}, T1 {B0,B1}; wait all but newest 2 halves
    STG(0, 2); STG(0, 3); STG(0, 0); STG(0, 1);
    STG(1, 2); STG(1, 3);
    asm volatile("s_waitcnt vmcnt(4)" ::: "memory");
    asm volatile("s_barrier" ::: "memory");

    for (int j = 0; j < nt; j += 2) {
        // K-tile j in buf0 (phases 1-4), j+1 in buf1 (phases 5-8)
        PHASE(0, 0, 1, 1, bF0, 0,     j + 1, 0, 0)   // stage A0(j+1)
        PHASE(0, 1, 0, 1, bF1, 0,     j + 1, 1, 0)   // stage A1(j+1)
        PHASE(1, 1, 1, 0, bF1, 0,     j + 2, 2, 0)   // stage B0(j+2)
        PHASE(1, 0, 0, 0, bF0, 0,     j + 2, 3, 1)   // stage B1(j+2), vmcnt(4)
        PHASE(0, 0, 1, 1, bF0, 32768, j + 2, 0, 0)   // stage A0(j+2)
        PHASE(0, 1, 0, 1, bF1, 32768, j + 2, 1, 0)   // stage A1(j+2)
        PHASE(1, 1, 1, 0, bF1, 32768, j + 3, 2, 0)   // stage B0(j+3)
        PHASE(1, 0, 0, 0, bF0, 32768, j + 3, 3, 1)   // stage B1(j+3), vmcnt(4)
    }
#undef PHASE

    // drain in-flight LDS-DMA (dead-slot stages); then LDS is dead storage
    asm volatile("s_waitcnt vmcnt(0)" ::: "memory");

    if (sizeof(OutT) == 4) {
        // fp32 path: direct stores (col = lane&15, row = (lane>>4)*4 + r)
        #pragma unroll
        for (int nj = 0; nj < 4; ++nj) {
            const int col = n0 + wc * 64 + nj * 16 + lr;
            const float bv = BIAS ? bias[col] : 0.f;
            #pragma unroll
            for (int mi = 0; mi < 8; ++mi) {
                const int row0 = i0 + wr * 128 + mi * 16 + lg * 4;
                #pragma unroll
                for (int r = 0; r < 4; ++r) {
                    float val = acc[mi][nj][r] * scale + bv;
                    if (RELU) val = fmaxf(val, 0.f);
                    ((float*)C)[(long)(row0 + r) * ldc + col] = val;
                }
            }
        }
    } else {
        // bf16 path: stage C tile (256x256 u16) in LDS with chunk-XOR
        // swizzle, then coalesced 512B-per-row u16x8 stores.
        __syncthreads();   // ALL waves' DMAs drained before LDS reuse
        #pragma unroll
        for (int nj = 0; nj < 4; ++nj) {
            const int cl = wc * 64 + nj * 16 + lr;      // tile-local col
            const float bv = BIAS ? bias[n0 + cl] : 0.f;
            #pragma unroll
            for (int mi = 0; mi < 8; ++mi) {
                const int rb = wr * 128 + mi * 16 + lg * 4;  // tile-local row
                const int sw = ((cl >> 3) ^ ((rb >> 2) & 7)) << 3;
                #pragma unroll
                for (int r = 0; r < 4; ++r) {
                    float val = acc[mi][nj][r] * scale + bv;
                    if (RELU) val = fmaxf(val, 0.f);
                    lds[(rb + r) * 256 + sw + (cl & 7)] = f2bf(val);
                }
            }
        }
        __syncthreads();
        #pragma unroll
        for (int i = 0; i < 16; ++i) {
            const int idx = i * 512 + t;
            const int row = idx >> 5;       // 32 chunks of 16B per row
            const int ch  = idx & 31;
            const int sw  = ch ^ ((row >> 2) & 7);
            const u16x8 v = *(const u16x8*)(lds + row * 256 + sw * 8);
            *(u16x8*)&((u16*)C)[(long)(i0 + row) * ldc + n0 + ch * 8] = v;
        }
    }
}

// ---------------------------------------------------------------------------
// fp32 -> bf16 elementwise convert (n multiple of 2048)
// ---------------------------------------------------------------------------
__global__ __launch_bounds__(256) void f2b_kernel(
    const float* __restrict__ in, u16* __restrict__ out)
{
    const long i = ((long)blockIdx.x * 256 + threadIdx.x) * 8;
    const float4 a = *(const float4*)(in + i);
    const float4 b = *(const float4*)(in + i + 4);
    u16x8 o;
    o[0] = f2bf(a.x); o[1] = f2bf(a.y); o[2] = f2bf(a.z); o[3] = f2bf(a.w);
    o[4] = f2bf(b.x); o[5] = f2bf(b.y); o[6] = f2bf(b.z); o[7] = f2bf(b.w);
    *(u16x8*)(out + i) = o;
}

// ---------------------------------------------------------------------------
// batched transpose of six DxD fp32 weights -> bf16 [D][D] slices (z = 0..5)
// ---------------------------------------------------------------------------
struct SrcPtrs6 { const float* p[6]; };
__global__ __launch_bounds__(256) void transpose6_f2b_kernel(
    SrcPtrs6 srcs, u16* __restrict__ outb)
{
    const float* in = srcs.p[blockIdx.z];
    u16* out = outb + (size_t)blockIdx.z * DD * DD;
    __shared__ float tile[32][33];
    const int tx = threadIdx.x & 31, ty = threadIdx.x >> 5;
    const int c0 = blockIdx.x * 32, r0 = blockIdx.y * 32;
    #pragma unroll
    for (int i = 0; i < 4; ++i)
        tile[ty + i * 8][tx] = in[(long)(r0 + ty + i * 8) * DD + c0 + tx];
    __syncthreads();
    #pragma unroll
    for (int i = 0; i < 4; ++i)
        out[(long)(c0 + ty + i * 8) * DD + r0 + tx] = f2bf(tile[tx][ty + i * 8]);
}

// ---------------------------------------------------------------------------
// transpose fp32 [R][C] -> bf16 [C][R]  (W1/W2; R,C multiples of 32)
// ---------------------------------------------------------------------------
__global__ __launch_bounds__(256) void transpose_f2b_kernel(
    const float* __restrict__ in, u16* __restrict__ out, int R, int C)
{
    __shared__ float tile[32][33];
    const int tx = threadIdx.x & 31, ty = threadIdx.x >> 5;
    const int c0 = blockIdx.x * 32, r0 = blockIdx.y * 32;
    #pragma unroll
    for (int i = 0; i < 4; ++i)
        tile[ty + i * 8][tx] = in[(long)(r0 + ty + i * 8) * C + c0 + tx];
    __syncthreads();
    #pragma unroll
    for (int i = 0; i < 4; ++i)
        out[(long)(c0 + ty + i * 8) * R + r0 + tx] = f2bf(tile[tx][ty + i * 8]);
}

// ---------------------------------------------------------------------------
// Row softmax on bf16 scores in place (-> probabilities bf16). fp32 math.
// Causal: threads whose 8-col span lies in a 256-col chunk with base > i
// skip load AND store -- those cols are never read by the CKEND PV
// (PV for row block [i0,i0+256) reads cols < i0+256 only).
// ---------------------------------------------------------------------------
__global__ __launch_bounds__(256) void softmax_bf16_kernel(
    u16* __restrict__ S, int L, int causal, long sSz)
{
    const int i = blockIdx.x;
    u16* row = S + (long)blockIdx.y * sSz + (long)i * L;
    const int t = threadIdx.x;

    const bool act = !causal || (((t >> 5) << 8) <= i);
    u16x8 rv = {0, 0, 0, 0, 0, 0, 0, 0};
    if (act) rv = *(const u16x8*)(row + t * 8);
    float v[8];
    float m = -INFINITY;
    #pragma unroll
    for (int e = 0; e < 8; ++e) {
        const int j = t * 8 + e;
        float val = (!act || (causal && j > i)) ? -INFINITY : bf2f(rv[e]);
        v[e] = val;
        m = fmaxf(m, val);
    }
    #pragma unroll
    for (int o = 32; o > 0; o >>= 1) m = fmaxf(m, __shfl_down(m, o, 64));
    __shared__ float redm[4];
    if ((t & 63) == 0) redm[t >> 6] = m;
    __syncthreads();
    m = fmaxf(fmaxf(redm[0], redm[1]), fmaxf(redm[2], redm[3]));

    float sum = 0.f;
    #pragma unroll
    for (int e = 0; e < 8; ++e) { float ex = __expf(v[e] - m); v[e] = ex; sum += ex; }
    #pragma unroll
    for (int o = 32; o > 0; o >>= 1) sum += __shfl_down(sum, o, 64);
    __shared__ float reds[4];
    if ((t & 63) == 0) reds[t >> 6] = sum;
    __syncthreads();
    sum = reds[0] + reds[1] + reds[2] + reds[3];

    if (act) {
        const float inv = 1.0f / sum;
        u16x8 ov;
        #pragma unroll
        for (int e = 0; e < 8; ++e) ov[e] = f2bf(v[e] * inv);
        *(u16x8*)(row + t * 8) = ov;
    }
}

// ---------------------------------------------------------------------------
// out = LayerNorm(x + y; gamma, beta, eps=1e-3), D=1024; optional bf16 copy.
// Y is fp32 or bf16 (YT = float / u16).
// ---------------------------------------------------------------------------
template <typename YT>
__global__ __launch_bounds__(256) void add_ln_kernel(
    const float* __restrict__ X, const YT* __restrict__ Y,
    const float* __restrict__ gamma, const float* __restrict__ beta,
    float* __restrict__ out, u16* __restrict__ outb, int D)
{
    const long r = blockIdx.x;
    const int t = threadIdx.x;
    const float4 x = *(const float4*)&X[r * D + t * 4];
    float y0, y1, y2, y3;
    if (sizeof(YT) == 4) {
        const float4 y = *(const float4*)&((const float*)Y)[r * D + t * 4];
        y0 = y.x; y1 = y.y; y2 = y.z; y3 = y.w;
    } else {
        const u16x4 y = *(const u16x4*)&((const u16*)Y)[r * D + t * 4];
        y0 = bf2f(y[0]); y1 = bf2f(y[1]); y2 = bf2f(y[2]); y3 = bf2f(y[3]);
    }
    float s0 = x.x + y0, s1 = x.y + y1, s2 = x.z + y2, s3 = x.w + y3;

    float sum = s0 + s1 + s2 + s3;
    float sq  = s0 * s0 + s1 * s1 + s2 * s2 + s3 * s3;
    #pragma unroll
    for (int o = 32; o > 0; o >>= 1) {
        sum += __shfl_down(sum, o, 64);
        sq  += __shfl_down(sq, o, 64);
    }
    __shared__ float rsum[4], rsq[4];
    if ((t & 63) == 0) { rsum[t >> 6] = sum; rsq[t >> 6] = sq; }
    __syncthreads();
    sum = rsum[0] + rsum[1] + rsum[2] + rsum[3];
    sq  = rsq[0] + rsq[1] + rsq[2] + rsq[3];

    const float mu   = sum / (float)D;
    const float var  = sq / (float)D - mu * mu;
    const float rstd = rsqrtf(var + 1e-3f);

    const float4 g = *(const float4*)&gamma[t * 4];
    const float4 b = *(const float4*)&beta[t * 4];
    float4 o;
    o.x = (s0 - mu) * rstd * g.x + b.x;
    o.y = (s1 - mu) * rstd * g.y + b.y;
    o.z = (s2 - mu) * rstd * g.z + b.z;
    o.w = (s3 - mu) * rstd * g.w + b.w;
    *(float4*)&out[r * D + t * 4] = o;
    if (outb) {
        u16x4 ob;
        ob[0] = f2bf(o.x); ob[1] = f2bf(o.y); ob[2] = f2bf(o.z); ob[3] = f2bf(o.w);
        *(u16x4*)&outb[r * D + t * 4] = ob;
    }
}

// ---------------------------------------------------------------------------
extern "C" void kernel_launch(void* const* d_in, const int* in_sizes, int n_in,
                              void* d_out, int out_size, void* d_ws, size_t ws_size,
                              hipStream_t stream)
{
    const int B = BB, L = LL_, D = DD, H = HH;
    const long LD  = (long)L * D;        // 2M elems
    const long LLs = (long)L * L;        // 4M elems
    const long BLD = (long)B * LD;       // 16.78M elems
    const int  BL  = B * L;              // 16384
    const int  D2  = 2 * D;              // fused QK width
    const long DDl = (long)D * D;

    const float* x     = (const float*)d_in[0];
    const float* ctx   = (const float*)d_in[1];
    const float* Wk_s  = (const float*)d_in[2];
    const float* Wv_s  = (const float*)d_in[3];
    const float* Wq_s  = (const float*)d_in[4];
    const float* Wk_c  = (const float*)d_in[5];
    const float* Wv_c  = (const float*)d_in[6];
    const float* Wq_c  = (const float*)d_in[7];
    const float* W1    = (const float*)d_in[8];
    const float* b1    = (const float*)d_in[9];
    const float* W2    = (const float*)d_in[10];
    const float* b2    = (const float*)d_in[11];
    const float* gamma = (const float*)d_in[12];
    const float* beta  = (const float*)d_in[13];
    float* out = (float*)d_out;

    // ---- workspace layout (bump allocator) ----
    size_t ofs = 0;
    auto alloc = [&](size_t bytes) -> char* {
        char* p = (char*)d_ws + ofs;
        ofs += (bytes + 255) & ~(size_t)255;
        return p;
    };
    // wT slices: 0=Wq_s^T 1=Wk_s^T 2=Wv_s^T 3=Wq_c^T 4=Wk_c^T 5=Wv_c^T
    u16* wT   = (u16*)alloc((size_t)6 * DDl * 2);
    u16* W1T  = (u16*)alloc((size_t)D * H * 2);       // [H][D]
    u16* W2T  = (u16*)alloc((size_t)H * D * 2);       // [D][H]
    u16* actb1 = (u16*)alloc((size_t)BLD * 2);    // xb -> ctxb -> o2b
    u16* actb2 = (u16*)alloc((size_t)BLD * 2);    // o1b   (= actb1 + BLD)
    float* o2  = (float*)alloc((size_t)BLD * 4);
    char* scratch = (char*)d_ws + ofs;
    const size_t remain = ws_size > ofs ? ws_size - ofs : 0;

    // per-batch attention scratch: qk [L][2D] + vt [D][L] + P [L][L]
    // + attn [L][D], all bf16
    const size_t per_b = (size_t)(2 * LD + LD + LLs + LD) * 2;
    long gl = (long)(remain / per_b);
    const int g = gl < 1 ? 1 : (gl > B ? B : (int)gl);

    u16* qkb  = (u16*)scratch;                       // [g*L][2D]
    u16* vtb  = qkb + (size_t)g * L * D2;            // [g][D][L]
    u16* Pb   = vtb + (size_t)g * LD;                // [g][L][L]
    u16* attnb = Pb + (size_t)g * LLs;               // [g][L][D] bf16

    const float scale = 1.0f / sqrtf((float)L);
    const dim3 blk(256);
    const dim3 blk512(512);
    const long L2D = (long)L * D2;

    // ---- weight transposes (fp32 -> bf16): 6 DxD batched + W1 + W2 ----
    SrcPtrs6 sp;
    sp.p[0] = Wq_s; sp.p[1] = Wk_s; sp.p[2] = Wv_s;
    sp.p[3] = Wq_c; sp.p[4] = Wk_c; sp.p[5] = Wv_c;
    transpose6_f2b_kernel<<<dim3(D/32, D/32, 6), blk, 0, stream>>>(sp, wT);
    transpose_f2b_kernel<<<dim3(H/32, D/32), blk, 0, stream>>>(W1, W1T, D, H);
    transpose_f2b_kernel<<<dim3(D/32, H/32), blk, 0, stream>>>(W2, W2T, H, D);

    // V^T via swapped-operand GEMM: vt[d][l] = sum_k Wv[k][d] * src[l][k]
    auto vt_gemm = [&](const u16* WvT, const u16* srcb, long off, int gb) {
        gemm256_kernel<u16, false, false, false, false>
            <<<dim3(L/256, D/256, gb), blk512, 0, stream>>>(
                WvT, srcb + off, nullptr, vtb, D, L, 1.f,
                D, D, L, 0, LD, LD);
    };

    // attention tail (shared): scores, softmax, PV, add+LN
    auto attn_tail = [&](int gb, long off, const float* resid, float* dst,
                         u16* dstb, int causal) {
        if (causal) {
            gemm256_kernel<u16, false, false, true, false>
                <<<dim3(L/256, L/256, gb), blk512, 0, stream>>>(
                    qkb, qkb + D, nullptr, Pb, D, L, scale,
                    D2, D2, L, L2D, L2D, LLs);
        } else {
            gemm256_kernel<u16, false, false, false, false>
                <<<dim3(L/256, L/256, gb), blk512, 0, stream>>>(
                    qkb, qkb + D, nullptr, Pb, D, L, scale,
                    D2, D2, L, L2D, L2D, LLs);
        }
        softmax_bf16_kernel<<<dim3(L, gb), blk, 0, stream>>>(Pb, L, causal, LLs);
        if (causal) {
            gemm256_kernel<u16, false, false, false, true>
                <<<dim3(D/256, L/256, gb), blk512, 0, stream>>>(
                    Pb, vtb, nullptr, attnb, L, D, 1.f,
                    L, L, D, LLs, LD, LD);
        } else {
            gemm256_kernel<u16, false, false, false, false>
                <<<dim3(D/256, L/256, gb), blk512, 0, stream>>>(
                    Pb, vtb, nullptr, attnb, L, D, 1.f,
                    L, L, D, LLs, LD, LD);
        }
        add_ln_kernel<u16><<<dim3(gb * L), blk, 0, stream>>>(
            resid + off, attnb, gamma, beta, dst + off,
            dstb ? dstb + off : nullptr, D);
    };

    // ---- Phase A: self-attention (causal). o1 fp32 -> d_out, o1b -> actb2 ----
    f2b_kernel<<<dim3(BLD / 2048), blk, 0, stream>>>(x, actb1);       // xb
    for (int b0 = 0; b0 < B; b0 += g) {
        const int gb = (B - b0) < g ? (B - b0) : g;
        const long off = (long)b0 * LD;
        // fused QK projection: [gb*L, D] x [D, 2D]  (wT slices 0,1)
        gemm256_kernel<u16, false, false, false, false>
            <<<dim3(D2/256, gb*L/256), blk512, 0, stream>>>(
                actb1 + off, wT, nullptr, qkb, D, D2, 1.f,
                D, D, D2, 0, 0, 0);
        vt_gemm(wT + 2 * DDl, actb1, off, gb);
        attn_tail(gb, off, x, out, actb2, 1);
    }

    // ---- Phase B: cross-attention. o2 fp32 -> ws, o2b -> actb1 ----
    f2b_kernel<<<dim3(BLD / 2048), blk, 0, stream>>>(ctx, actb1);     // ctxb
    for (int b0 = 0; b0 < B; b0 += g) {
        const int gb = (B - b0) < g ? (B - b0) : g;
        const long off = (long)b0 * LD;
        // Q (z=0, A=actb2, B=Wq_c^T) and K (z=1, A=actb1, B=Wk_c^T) in one
        // dispatch: sAz = actb1 - actb2 = -BLD, sBz = DD, sCz = D.
        gemm256_kernel<u16, false, false, false, false>
            <<<dim3(D/256, gb*L/256, 2), blk512, 0, stream>>>(
                actb2 + off, wT + 3 * DDl, nullptr, qkb, D, D, 1.f,
                D, D, D2, -(long)BLD, DDl, (long)D);
        vt_gemm(wT + 5 * DDl, actb1, off, gb);
        attn_tail(gb, off, out, o2, actb1, 0);
    }

    // ---- Phase C: FFN + LN, row-chunked through scratch ----
    {
        long mc = (long)(remain / ((size_t)H * 2 + (size_t)D * 2));
        mc = (mc / 256) * 256;
        if (mc > BL) mc = BL;
        if (mc < 256) mc = 256;
        for (long m0 = 0; m0 < BL; m0 += mc) {
            const long rows = (BL - m0) < mc ? (BL - m0) : mc;
            u16* h = (u16*)scratch;                          // [rows, H] bf16
            u16* ff = (u16*)(scratch + (size_t)rows * H * 2);  // [rows, D] bf16
            gemm256_kernel<u16, true, true, false, false>
                <<<dim3(H/256, rows/256), blk512, 0, stream>>>(
                    actb1 + m0 * D, W1T, b1, h, D, H, 1.f,
                    D, D, H, 0, 0, 0);
            gemm256_kernel<u16, true, false, false, false>
                <<<dim3(D/256, rows/256), blk512, 0, stream>>>(
                    h, W2T, b2, ff, H, D, 1.f,
                    H, H, D, 0, 0, 0);
            add_ln_kernel<u16><<<dim3(rows), blk, 0, stream>>>(
                o2 + m0 * D, ff, gamma, beta, out + m0 * D, nullptr, D);
        }
    }
}